// Round 1
// baseline (1003.175 us; speedup 1.0000x reference)
//
#include <hip/hip_runtime.h>

#define BB 16
#define PP 131072
#define GG 64
#define THRESH 0.35f

// ---------------- workspace layout (bytes) ----------------
// zero region (memset each launch):
#define OFF_BESTPK   0                         // u64[BB*GG]          8192
#define OFF_H1       8192                      // u32[BB*4096]        262144
#define OFF_H2       270336                    // u32[BB*1024]        65536
#define OFF_H3       335872                    // u32[BB*1024]        65536
#define OFF_NPOS     401408                    // i32[BB]
#define OFF_KIMG     401472                    // i32[BB]
#define OFF_POSCLS   401536                    // f32[BB]
#define OFF_NEGSUM   401600                    // f32[BB]
#define OFF_LOCSUM   401664                    // f32[BB]
#define OFF_SELB1    401728                    // u32[BB]
#define OFF_KK1      401792                    // i32[BB]
#define OFF_SELB2    401856                    // u32[BB]
#define OFF_KK2      401920                    // i32[BB]
#define OFF_KSTAR    401984                    // u32[BB]
#define OFF_NEEDEQ   402048                    // i32[BB]
#define ZERO_BYTES   402112
// not zeroed (fully rewritten each launch):
#define OFF_KEYS     405504                    // u32[BB*PP]   8388608
#define OFF_BTO      8794112                   // f32[BB*PP]   8388608
#define OFF_BTI      17182720                  // u8 [BB*PP]   2097152
// total ~19.3 MB

// ---------------- match kernel ----------------
// grid (PP/1024, BB), block 256; each thread handles 4 priors x 64 gts.
__global__ __launch_bounds__(256) void k_match(
    const float* __restrict__ priorbox, const float* __restrict__ targets,
    unsigned long long* __restrict__ bestpk, float* __restrict__ bto,
    unsigned char* __restrict__ bti)
{
    __shared__ float gx1[GG], gy1[GG], gx2[GG], gy2[GG], gar[GG];
    __shared__ unsigned long long sbest[GG];
    const int b = blockIdx.y;
    const int tid = threadIdx.x;
    if (tid < GG) {
        const float* t = targets + (size_t)(b * GG + tid) * 5;
        float x1 = t[1], y1 = t[0], x2 = t[3], y2 = t[2];  // gts = t[[1,0,3,2]]
        gx1[tid] = x1; gy1[tid] = y1; gx2[tid] = x2; gy2[tid] = y2;
        gar[tid] = (x2 - x1) * (y2 - y1);
        sbest[tid] = 0ull;
    }
    __syncthreads();

    const int p0 = blockIdx.x * 1024 + tid * 4;
    float px1[4], py1[4], px2[4], py2[4], par[4];
#pragma unroll
    for (int j = 0; j < 4; j++) {
        float4 pr = *reinterpret_cast<const float4*>(priorbox + (size_t)(p0 + j) * 4);
        float hx = 0.5f * pr.z, hy = 0.5f * pr.w;
        px1[j] = pr.x - hx; py1[j] = pr.y - hy;
        px2[j] = pr.x + hx; py2[j] = pr.y + hy;
        par[j] = (px2[j] - px1[j]) * (py2[j] - py1[j]);
    }

    float bv[4] = {-1.f, -1.f, -1.f, -1.f};
    int   bg[4] = {64, 64, 64, 64};
    const int lane = tid & 63;

    for (int r = 0; r < GG; r++) {
        const int g = (lane + r) & 63;               // stagger: 64 lanes -> 64 distinct slots
        const float ax1 = gx1[g], ay1 = gy1[g], ax2 = gx2[g], ay2 = gy2[g], aar = gar[g];
        unsigned long long cand = 0ull;
#pragma unroll
        for (int j = 0; j < 4; j++) {
            float w = fminf(ax2, px2[j]) - fmaxf(ax1, px1[j]);
            float h = fminf(ay2, py2[j]) - fmaxf(ay1, py1[j]);
            w = fmaxf(w, 0.f); h = fmaxf(h, 0.f);
            float inter = w * h;
            float uni = aar + par[j] - inter;
            float v = inter * __builtin_amdgcn_rcpf(uni);
            // per-prior argmax over g, first-max (smallest g) tie-break
            if (v > bv[j] || (v == bv[j] && g < bg[j])) { bv[j] = v; bg[j] = g; }
            // per-g argmax over p: pack (iou_bits, ~p) -> max picks max iou, smallest p
            unsigned long long pk =
                ((unsigned long long)__float_as_uint(v) << 32) |
                (unsigned long long)(0xFFFFFFFFu - (unsigned)(p0 + j));
            cand = cand > pk ? cand : pk;
        }
        atomicMax(&sbest[g], cand);
    }

    *reinterpret_cast<float4*>(bto + (size_t)b * PP + p0) =
        make_float4(bv[0], bv[1], bv[2], bv[3]);
    *reinterpret_cast<uchar4*>(bti + (size_t)b * PP + p0) =
        make_uchar4((unsigned char)bg[0], (unsigned char)bg[1],
                    (unsigned char)bg[2], (unsigned char)bg[3]);

    __syncthreads();
    if (tid < GG) atomicMax(&bestpk[b * GG + tid], sbest[tid]);
}

// ---------------- decode best priors + override ----------------
// one block, BB threads; per image sequential g loop => later g wins on duplicates
__global__ void k_decode(const unsigned long long* __restrict__ bestpk,
                         float* __restrict__ bto, unsigned char* __restrict__ bti)
{
    const int b = threadIdx.x;
    if (b >= BB) return;
    for (int g = 0; g < GG; g++) {
        unsigned long long pk = bestpk[b * GG + g];
        unsigned p = 0xFFFFFFFFu - (unsigned)(pk & 0xFFFFFFFFull);
        bto[(size_t)b * PP + p] = 2.0f;
        bti[(size_t)b * PP + p] = (unsigned char)g;
    }
}

// ---------------- loss pass ----------------
// grid (PP/256, BB), block 256
__global__ __launch_bounds__(256) void k_loss(
    const float* __restrict__ loc_preds, const float* __restrict__ cls_preds,
    const float* __restrict__ priorbox, const float* __restrict__ targets,
    const float* __restrict__ bto, const unsigned char* __restrict__ bti,
    unsigned* __restrict__ keys, unsigned* __restrict__ h1,
    int* __restrict__ npos, float* __restrict__ posclssum, float* __restrict__ locsum)
{
    __shared__ float gx1[GG], gy1[GG], gx2[GG], gy2[GG], glab[GG];
    __shared__ unsigned hist[4096];
    const int b = blockIdx.y;
    const int tid = threadIdx.x;
    for (int i = tid; i < 4096; i += 256) hist[i] = 0;
    if (tid < GG) {
        const float* t = targets + (size_t)(b * GG + tid) * 5;
        gx1[tid] = t[1]; gy1[tid] = t[0]; gx2[tid] = t[3]; gy2[tid] = t[2];
        glab[tid] = t[4];
    }
    __syncthreads();

    const int p = blockIdx.x * 256 + tid;
    const size_t ip = (size_t)b * PP + p;
    const float bv = bto[ip];
    const int g = bti[ip];
    const float2 cl = *reinterpret_cast<const float2*>(cls_preds + ip * 2);
    const float mx = fmaxf(cl.x, cl.y);
    const float lse = mx + log1pf(expf(fminf(cl.x, cl.y) - mx));
    const float conf = (bv < THRESH) ? 0.f : glab[g];
    const bool pos = conf > 0.f;

    float locpart = 0.f, clspart = 0.f; int cnt = 0;
    unsigned key = 0u;
    if (pos) {
        int lbl = (int)conf;                       // labels are 1.0
        float gathered = (lbl == 0) ? cl.x : cl.y;
        clspart = lse - gathered;
        cnt = 1;
        float4 pr = *reinterpret_cast<const float4*>(priorbox + (size_t)p * 4);
        float mx1 = gx1[g], my1 = gy1[g], mx2 = gx2[g], my2 = gy2[g];
        float gcx = ((mx1 + mx2) * 0.5f - pr.x) / (0.1f * pr.z);
        float gcy = ((my1 + my2) * 0.5f - pr.y) / (0.1f * pr.w);
        float gw = logf((mx2 - mx1) / pr.z) / 0.2f;
        float gh = logf((my2 - my1) / pr.w) / 0.2f;
        float4 lp = *reinterpret_cast<const float4*>(loc_preds + ip * 4);
        float d0 = lp.x - gcx, d1 = lp.y - gcy, d2 = lp.z - gw, d3 = lp.w - gh;
        float a0 = fabsf(d0), a1 = fabsf(d1), a2 = fabsf(d2), a3 = fabsf(d3);
        float s0 = (a0 < 1.f) ? 0.5f * d0 * d0 : a0 - 0.5f;
        float s1 = (a1 < 1.f) ? 0.5f * d1 * d1 : a1 - 0.5f;
        float s2 = (a2 < 1.f) ? 0.5f * d2 * d2 : a2 - 0.5f;
        float s3 = (a3 < 1.f) ? 0.5f * d3 * d3 : a3 - 0.5f;
        locpart = s0 + s1 + s2 + s3;
    } else {
        key = __float_as_uint(lse - cl.x);          // loss_c > 0 strictly
    }
    keys[ip] = key;
    atomicAdd(&hist[key >> 20], 1u);

    for (int o = 32; o; o >>= 1) {
        locpart += __shfl_xor(locpart, o);
        clspart += __shfl_xor(clspart, o);
        cnt     += __shfl_xor(cnt, o);
    }
    if ((tid & 63) == 0) {
        if (cnt)            atomicAdd(&npos[b], cnt);
        if (clspart != 0.f) atomicAdd(&posclssum[b], clspart);
        if (locpart != 0.f) atomicAdd(&locsum[b], locpart);
    }
    __syncthreads();
    for (int i = tid; i < 4096; i += 256) {
        unsigned c = hist[i];
        if (c) atomicAdd(&h1[b * 4096 + i], c);
    }
}

// ---------------- descending k-th finder ----------------
template <int NBINS>
__device__ void find_kth(const unsigned* __restrict__ h, int k, int* sel, int* krem)
{
    constexpr int PER = NBINS / 256;
    __shared__ unsigned part[256];
    __shared__ int res[2];
    const int tid = threadIdx.x;
    unsigned s = 0;
#pragma unroll
    for (int i = 0; i < PER; i++) s += h[NBINS - 1 - (tid * PER + i)];
    part[tid] = s;
    __syncthreads();
    if (tid == 0) {
        int fsel = -1, fk = 0;
        if (k > 0) {
            unsigned run = 0;
            for (int t = 0; t < 256; t++) {
                if (run + part[t] >= (unsigned)k) {
                    for (int i = 0; i < PER; i++) {
                        int bin = NBINS - 1 - (t * PER + i);
                        unsigned hv = h[bin];
                        run += hv;
                        if (run >= (unsigned)k) { fsel = bin; fk = k - (int)(run - hv); break; }
                    }
                    break;
                }
                run += part[t];
            }
        }
        res[0] = fsel; res[1] = fk;
    }
    __syncthreads();
    *sel = res[0]; *krem = res[1];
}

__global__ __launch_bounds__(256) void k_scan1(const unsigned* __restrict__ h1,
                                               const int* __restrict__ npos,
                                               int* __restrict__ kimg,
                                               unsigned* __restrict__ selb1,
                                               int* __restrict__ kk1)
{
    const int b = blockIdx.x;
    const int k = min(3 * npos[b], PP - 1);
    int sel, krem;
    find_kth<4096>(h1 + b * 4096, k, &sel, &krem);
    if (threadIdx.x == 0) {
        kimg[b] = k;
        selb1[b] = (sel < 0) ? 0xFFFFFFFFu : (unsigned)sel;
        kk1[b] = krem;
    }
}

__global__ void k_h2(const unsigned* __restrict__ keys,
                     const unsigned* __restrict__ selb1, unsigned* __restrict__ h2)
{
    const int b = blockIdx.y;
    const unsigned s = selb1[b];
    const unsigned key = keys[(size_t)b * PP + blockIdx.x * 256 + threadIdx.x];
    if ((key >> 20) == s) atomicAdd(&h2[b * 1024 + ((key >> 10) & 1023u)], 1u);
}

__global__ __launch_bounds__(256) void k_scan2(const unsigned* __restrict__ h2,
                                               const int* __restrict__ kk1,
                                               unsigned* __restrict__ selb2,
                                               int* __restrict__ kk2)
{
    const int b = blockIdx.x;
    int sel, krem;
    find_kth<1024>(h2 + b * 1024, kk1[b], &sel, &krem);
    if (threadIdx.x == 0) {
        selb2[b] = (sel < 0) ? 0xFFFFFFFFu : (unsigned)sel;
        kk2[b] = krem;
    }
}

__global__ void k_h3(const unsigned* __restrict__ keys,
                     const unsigned* __restrict__ selb1,
                     const unsigned* __restrict__ selb2, unsigned* __restrict__ h3)
{
    const int b = blockIdx.y;
    const unsigned top = (selb1[b] << 10) | selb2[b];
    const unsigned key = keys[(size_t)b * PP + blockIdx.x * 256 + threadIdx.x];
    if ((key >> 10) == top) atomicAdd(&h3[b * 1024 + (key & 1023u)], 1u);
}

__global__ __launch_bounds__(256) void k_scan3(const unsigned* __restrict__ h3,
                                               const int* __restrict__ kk2,
                                               const unsigned* __restrict__ selb1,
                                               const unsigned* __restrict__ selb2,
                                               unsigned* __restrict__ Kstar,
                                               int* __restrict__ needeq)
{
    const int b = blockIdx.x;
    int sel, krem;
    find_kth<1024>(h3 + b * 1024, kk2[b], &sel, &krem);
    if (threadIdx.x == 0) {
        if (sel < 0) { Kstar[b] = 0xFFFFFFFFu; needeq[b] = 0; }
        else {
            Kstar[b] = (selb1[b] << 20) | (selb2[b] << 10) | (unsigned)sel;
            needeq[b] = krem;
        }
    }
}

__global__ __launch_bounds__(256) void k_neg(const unsigned* __restrict__ keys,
                                             const unsigned* __restrict__ Kstar,
                                             float* __restrict__ negsum)
{
    const int b = blockIdx.y;
    const unsigned K = Kstar[b];
    const unsigned key = keys[(size_t)b * PP + blockIdx.x * 256 + threadIdx.x];
    float v = (key > K) ? __uint_as_float(key) : 0.f;
    for (int o = 32; o; o >>= 1) v += __shfl_xor(v, o);
    if ((threadIdx.x & 63) == 0 && v != 0.f) atomicAdd(&negsum[b], v);
}

__global__ void k_final(const int* __restrict__ npos, const int* __restrict__ kimg,
                        const float* __restrict__ posclssum, const float* __restrict__ negsum,
                        const float* __restrict__ locsum, const unsigned* __restrict__ Kstar,
                        const int* __restrict__ needeq, float* __restrict__ out)
{
    if (threadIdx.x == 0 && blockIdx.x == 0) {
        int npt = 0; long long maskc = 0; float clsnum = 0.f, locnum = 0.f;
        for (int b = 0; b < BB; b++) {
            npt += npos[b];
            maskc += (long long)npos[b] + kimg[b];
            float add = (needeq[b] > 0) ? needeq[b] * __uint_as_float(Kstar[b]) : 0.f;
            clsnum += posclssum[b] + negsum[b] + add;
            locnum += locsum[b];
        }
        float denom_loc = (float)((4 * npt > 1) ? 4 * npt : 1);
        float denom_cls = (float)((maskc > 1) ? maskc : 1);
        float loss_loc = locnum / denom_loc;
        float loss_cls = clsnum / denom_cls;
        float loss = (loss_cls + loss_loc) / (float)npt;
        out[0] = loss; out[1] = loss_loc; out[2] = loss_cls;
    }
}

extern "C" void kernel_launch(void* const* d_in, const int* in_sizes, int n_in,
                              void* d_out, int out_size, void* d_ws, size_t ws_size,
                              hipStream_t stream)
{
    const float* loc_preds = (const float*)d_in[0];
    const float* cls_preds = (const float*)d_in[1];
    const float* priorbox  = (const float*)d_in[2];
    const float* targets   = (const float*)d_in[3];
    float* out = (float*)d_out;

    char* ws = (char*)d_ws;
    unsigned long long* bestpk = (unsigned long long*)(ws + OFF_BESTPK);
    unsigned* h1     = (unsigned*)(ws + OFF_H1);
    unsigned* h2     = (unsigned*)(ws + OFF_H2);
    unsigned* h3     = (unsigned*)(ws + OFF_H3);
    int*      npos   = (int*)(ws + OFF_NPOS);
    int*      kimg   = (int*)(ws + OFF_KIMG);
    float*    poscls = (float*)(ws + OFF_POSCLS);
    float*    negsum = (float*)(ws + OFF_NEGSUM);
    float*    locsum = (float*)(ws + OFF_LOCSUM);
    unsigned* selb1  = (unsigned*)(ws + OFF_SELB1);
    int*      kk1    = (int*)(ws + OFF_KK1);
    unsigned* selb2  = (unsigned*)(ws + OFF_SELB2);
    int*      kk2    = (int*)(ws + OFF_KK2);
    unsigned* Kstar  = (unsigned*)(ws + OFF_KSTAR);
    int*      needeq = (int*)(ws + OFF_NEEDEQ);
    unsigned* keys   = (unsigned*)(ws + OFF_KEYS);
    float*    bto    = (float*)(ws + OFF_BTO);
    unsigned char* bti = (unsigned char*)(ws + OFF_BTI);

    hipMemsetAsync(d_ws, 0, ZERO_BYTES, stream);

    k_match<<<dim3(PP / 1024, BB), 256, 0, stream>>>(priorbox, targets, bestpk, bto, bti);
    k_decode<<<1, 64, 0, stream>>>(bestpk, bto, bti);
    k_loss<<<dim3(PP / 256, BB), 256, 0, stream>>>(loc_preds, cls_preds, priorbox, targets,
                                                   bto, bti, keys, h1, npos, poscls, locsum);
    k_scan1<<<BB, 256, 0, stream>>>(h1, npos, kimg, selb1, kk1);
    k_h2<<<dim3(PP / 256, BB), 256, 0, stream>>>(keys, selb1, h2);
    k_scan2<<<BB, 256, 0, stream>>>(h2, kk1, selb2, kk2);
    k_h3<<<dim3(PP / 256, BB), 256, 0, stream>>>(keys, selb1, selb2, h3);
    k_scan3<<<BB, 256, 0, stream>>>(h3, kk2, selb1, selb2, Kstar, needeq);
    k_neg<<<dim3(PP / 256, BB), 256, 0, stream>>>(keys, Kstar, negsum);
    k_final<<<1, 64, 0, stream>>>(npos, kimg, poscls, negsum, locsum, Kstar, needeq, out);
}

// Round 2
// 196.757 us; speedup vs baseline: 5.0986x; 5.0986x over previous
//
#include <hip/hip_runtime.h>

#define BB 16
#define PP 131072
#define GG 64
#define THRESH 0.35f

// ---------------- workspace layout (bytes) ----------------
#define OFF_BESTPK   0         // u64[BB*GG]    8192
#define OFF_H1       8192      // u32[BB*4096]  262144
#define OFF_H2       270336    // u32[BB*1024]  65536
#define OFF_H3       335872    // u32[BB*1024]  65536
#define OFF_NPOSR    401408    // i32[8][BB]    512
#define OFF_PCR      401920    // f32[8][BB]    512
#define OFF_LOCR     402432    // f32[8][BB]    512
#define OFF_NEGS     402944    // f32[BB]       64
#define OFF_KIMG     403008    // i32[BB]
#define OFF_SELB1    403072    // u32[BB]
#define OFF_KK1      403136    // i32[BB]
#define OFF_SELB2    403200    // u32[BB]
#define OFF_KK2      403264    // i32[BB]
#define OFF_KSTAR    403328    // u32[BB]
#define OFF_NEEDEQ   403392    // i32[BB]
#define ZERO_BYTES   403456
#define OFF_KEYS     403456    // u32[BB*PP]  8388608
#define OFF_BTO      8792064   // f32[BB*PP]  8388608
#define OFF_BTI      17180672  // u8 [BB*PP]  2097152

// ---------------- match kernel ----------------
// grid (PP/2048, BB), block 256; each thread: 8 priors (strided by 256) x 64 gts
__global__ __launch_bounds__(256) void k_match(
    const float* __restrict__ priorbox, const float* __restrict__ targets,
    unsigned long long* __restrict__ bestpk, float* __restrict__ bto,
    unsigned char* __restrict__ bti)
{
    __shared__ float gx1[GG], gy1[GG], gx2[GG], gy2[GG], gar[GG];
    __shared__ unsigned long long sbest[GG];
    const int b = blockIdx.y;
    const int tid = threadIdx.x;
    if (tid < GG) {
        const float* t = targets + (size_t)(b * GG + tid) * 5;
        float x1 = t[1], y1 = t[0], x2 = t[3], y2 = t[2];  // gts = t[[1,0,3,2]]
        gx1[tid] = x1; gy1[tid] = y1; gx2[tid] = x2; gy2[tid] = y2;
        gar[tid] = (x2 - x1) * (y2 - y1);
        sbest[tid] = 0ull;
    }
    __syncthreads();

    const int pbase = blockIdx.x * 2048 + tid;
    float px1[8], py1[8], px2[8], py2[8], par[8];
#pragma unroll
    for (int j = 0; j < 8; j++) {
        float4 pr = *reinterpret_cast<const float4*>(priorbox + (size_t)(pbase + j * 256) * 4);
        float hx = 0.5f * pr.z, hy = 0.5f * pr.w;
        px1[j] = pr.x - hx; py1[j] = pr.y - hy;
        px2[j] = pr.x + hx; py2[j] = pr.y + hy;
        par[j] = (px2[j] - px1[j]) * (py2[j] - py1[j]);
    }

    // per-prior argmax over g packed: (iou_bits<<32)|(63-g): max iou, then min g
    unsigned long long bpk[8] = {0ull,0ull,0ull,0ull,0ull,0ull,0ull,0ull};

    for (int r = 0; r < GG; r++) {
        const int g = (tid + r) & 63;                // 64 lanes -> 64 distinct g
        const float ax1 = gx1[g], ay1 = gy1[g], ax2 = gx2[g], ay2 = gy2[g], aar = gar[g];
        unsigned long long cand = 0ull;
#pragma unroll
        for (int j = 0; j < 8; j++) {
            float w = fminf(ax2, px2[j]) - fmaxf(ax1, px1[j]);
            float h = fminf(ay2, py2[j]) - fmaxf(ay1, py1[j]);
            w = fmaxf(w, 0.f); h = fmaxf(h, 0.f);
            float inter = w * h;
            float v = inter * __builtin_amdgcn_rcpf(aar + par[j] - inter);
            unsigned long long hi = ((unsigned long long)__float_as_uint(v)) << 32;
            unsigned long long pg = hi | (unsigned long long)(63 - g);
            bpk[j] = bpk[j] > pg ? bpk[j] : pg;
            // per-g argmax over p: (iou_bits, ~p) -> max iou, then min p
            unsigned long long pp = hi |
                (unsigned long long)(0xFFFFFFFFu - (unsigned)(pbase + j * 256));
            cand = cand > pp ? cand : pp;
        }
        atomicMax(&sbest[g], cand);
    }

#pragma unroll
    for (int j = 0; j < 8; j++) {
        const int p = pbase + j * 256;
        bto[(size_t)b * PP + p] = __uint_as_float((unsigned)(bpk[j] >> 32));
        bti[(size_t)b * PP + p] = (unsigned char)(63u - (unsigned)(bpk[j] & 63ull));
    }

    __syncthreads();
    if (tid < GG) atomicMax(&bestpk[b * GG + tid], sbest[tid]);
}

// ---------------- decode best priors + override ----------------
// grid 16 blocks x 64 threads; prefetch via all lanes, serial g-loop => later g wins
__global__ void k_decode(const unsigned long long* __restrict__ bestpk,
                         float* __restrict__ bto, unsigned char* __restrict__ bti)
{
    __shared__ unsigned long long spk[GG];
    const int b = blockIdx.x;
    spk[threadIdx.x] = bestpk[b * GG + threadIdx.x];
    __syncthreads();
    if (threadIdx.x == 0) {
        for (int g = 0; g < GG; g++) {
            unsigned p = 0xFFFFFFFFu - (unsigned)(spk[g] & 0xFFFFFFFFull);
            bto[(size_t)b * PP + p] = 2.0f;
            bti[(size_t)b * PP + p] = (unsigned char)g;
        }
    }
}

// ---------------- loss pass (keys + pos sums; NO histogram) ----------------
// grid (PP/2048, BB), block 256, 8 priors/thread strided
__global__ __launch_bounds__(256) void k_loss(
    const float* __restrict__ loc_preds, const float* __restrict__ cls_preds,
    const float* __restrict__ priorbox, const float* __restrict__ targets,
    const float* __restrict__ bto, const unsigned char* __restrict__ bti,
    unsigned* __restrict__ keys,
    int* __restrict__ npos_r, float* __restrict__ poscls_r, float* __restrict__ locsum_r)
{
    __shared__ float gx1[GG], gy1[GG], gx2[GG], gy2[GG], glab[GG];
    __shared__ float sred[8];
    __shared__ int sredi[4];
    const int b = blockIdx.y;
    const int tid = threadIdx.x;
    if (tid < GG) {
        const float* t = targets + (size_t)(b * GG + tid) * 5;
        gx1[tid] = t[1]; gy1[tid] = t[0]; gx2[tid] = t[3]; gy2[tid] = t[2];
        glab[tid] = t[4];
    }
    __syncthreads();

    const int pbase = blockIdx.x * 2048 + tid;
    float locpart = 0.f, clspart = 0.f; int cnt = 0;

#pragma unroll
    for (int j = 0; j < 8; j++) {
        const int p = pbase + j * 256;
        const size_t ip = (size_t)b * PP + p;
        const float bv = bto[ip];
        const int g = bti[ip];
        const float2 cl = *reinterpret_cast<const float2*>(cls_preds + ip * 2);
        const float mx = fmaxf(cl.x, cl.y);
        const float lse = mx + log1pf(expf(fminf(cl.x, cl.y) - mx));
        const float conf = (bv < THRESH) ? 0.f : glab[g];
        unsigned key = 0u;
        if (conf > 0.f) {
            float gathered = (((int)conf) == 0) ? cl.x : cl.y;
            clspart += lse - gathered;
            cnt++;
            float4 pr = *reinterpret_cast<const float4*>(priorbox + (size_t)p * 4);
            float mx1 = gx1[g], my1 = gy1[g], mx2 = gx2[g], my2 = gy2[g];
            float gcx = ((mx1 + mx2) * 0.5f - pr.x) / (0.1f * pr.z);
            float gcy = ((my1 + my2) * 0.5f - pr.y) / (0.1f * pr.w);
            float gw = logf((mx2 - mx1) / pr.z) / 0.2f;
            float gh = logf((my2 - my1) / pr.w) / 0.2f;
            float4 lp = *reinterpret_cast<const float4*>(loc_preds + ip * 4);
            float d0 = lp.x - gcx, d1 = lp.y - gcy, d2 = lp.z - gw, d3 = lp.w - gh;
            float a0 = fabsf(d0), a1 = fabsf(d1), a2 = fabsf(d2), a3 = fabsf(d3);
            locpart += ((a0 < 1.f) ? 0.5f * d0 * d0 : a0 - 0.5f)
                     + ((a1 < 1.f) ? 0.5f * d1 * d1 : a1 - 0.5f)
                     + ((a2 < 1.f) ? 0.5f * d2 * d2 : a2 - 0.5f)
                     + ((a3 < 1.f) ? 0.5f * d3 * d3 : a3 - 0.5f);
        } else {
            key = __float_as_uint(lse - cl.x);       // loss_c > 0 strictly for negs
        }
        keys[ip] = key;
    }

    for (int o = 32; o; o >>= 1) {
        locpart += __shfl_xor(locpart, o);
        clspart += __shfl_xor(clspart, o);
        cnt     += __shfl_xor(cnt, o);
    }
    const int w = tid >> 6;
    if ((tid & 63) == 0) { sred[w] = locpart; sred[4 + w] = clspart; sredi[w] = cnt; }
    __syncthreads();
    if (tid == 0) {
        float l = sred[0] + sred[1] + sred[2] + sred[3];
        float c = sred[4] + sred[5] + sred[6] + sred[7];
        int   n = sredi[0] + sredi[1] + sredi[2] + sredi[3];
        const int rep = (blockIdx.x & 7) * BB + b;
        if (n)       atomicAdd(&npos_r[rep], n);
        if (c != 0.f) atomicAdd(&poscls_r[rep], c);
        if (l != 0.f) atomicAdd(&locsum_r[rep], l);
    }
}

// ---------------- histogram pass 1 (12-bit) ----------------
// grid (16, BB) x 1024 threads, 8 keys/thread
__global__ __launch_bounds__(1024) void k_hist1(const unsigned* __restrict__ keys,
                                                unsigned* __restrict__ h1)
{
    __shared__ unsigned hist[4096];
    const int b = blockIdx.y, tid = threadIdx.x;
    for (int i = tid; i < 4096; i += 1024) hist[i] = 0;
    __syncthreads();
    const size_t base = (size_t)b * PP + (size_t)blockIdx.x * 8192;
#pragma unroll
    for (int j = 0; j < 8; j++)
        atomicAdd(&hist[keys[base + j * 1024 + tid] >> 20], 1u);
    __syncthreads();
    for (int i = tid; i < 4096; i += 1024) {
        unsigned c = hist[i];
        if (c) atomicAdd(&h1[b * 4096 + i], c);
    }
}

// ---------------- descending k-th finder ----------------
template <int NBINS>
__device__ void find_kth(const unsigned* __restrict__ h, int k, int* sel, int* krem)
{
    constexpr int PER = NBINS / 256;
    __shared__ unsigned part[256];
    __shared__ int res[2];
    const int tid = threadIdx.x;
    unsigned s = 0;
#pragma unroll
    for (int i = 0; i < PER; i++) s += h[NBINS - 1 - (tid * PER + i)];
    part[tid] = s;
    __syncthreads();
    if (tid == 0) {
        int fsel = -1, fk = 0;
        if (k > 0) {
            unsigned run = 0;
            for (int t = 0; t < 256; t++) {
                if (run + part[t] >= (unsigned)k) {
                    for (int i = 0; i < PER; i++) {
                        int bin = NBINS - 1 - (t * PER + i);
                        unsigned hv = h[bin];
                        run += hv;
                        if (run >= (unsigned)k) { fsel = bin; fk = k - (int)(run - hv); break; }
                    }
                    break;
                }
                run += part[t];
            }
        }
        res[0] = fsel; res[1] = fk;
    }
    __syncthreads();
    *sel = res[0]; *krem = res[1];
}

__global__ __launch_bounds__(256) void k_scan1(const unsigned* __restrict__ h1,
                                               const int* __restrict__ npos_r,
                                               int* __restrict__ kimg,
                                               unsigned* __restrict__ selb1,
                                               int* __restrict__ kk1)
{
    const int b = blockIdx.x;
    int np = 0;
    for (int r = 0; r < 8; r++) np += npos_r[r * BB + b];
    const int k = min(3 * np, PP - 1);
    int sel, krem;
    find_kth<4096>(h1 + b * 4096, k, &sel, &krem);
    if (threadIdx.x == 0) {
        kimg[b] = k;
        selb1[b] = (sel < 0) ? 0xFFFFFFFFu : (unsigned)sel;
        kk1[b] = krem;
    }
}

// grid (4, BB) x 1024 threads, 32 keys/thread
__global__ __launch_bounds__(1024) void k_h2(const unsigned* __restrict__ keys,
                                             const unsigned* __restrict__ selb1,
                                             unsigned* __restrict__ h2)
{
    __shared__ unsigned hist[1024];
    const int b = blockIdx.y, tid = threadIdx.x;
    hist[tid] = 0;
    __syncthreads();
    const unsigned s = selb1[b];
    const size_t base = (size_t)b * PP + (size_t)blockIdx.x * 32768;
    for (int j = 0; j < 32; j++) {
        unsigned key = keys[base + j * 1024 + tid];
        if ((key >> 20) == s) atomicAdd(&hist[(key >> 10) & 1023u], 1u);
    }
    __syncthreads();
    unsigned c = hist[tid];
    if (c) atomicAdd(&h2[b * 1024 + tid], c);
}

__global__ __launch_bounds__(256) void k_scan2(const unsigned* __restrict__ h2,
                                               const int* __restrict__ kk1,
                                               unsigned* __restrict__ selb2,
                                               int* __restrict__ kk2)
{
    const int b = blockIdx.x;
    int sel, krem;
    find_kth<1024>(h2 + b * 1024, kk1[b], &sel, &krem);
    if (threadIdx.x == 0) {
        selb2[b] = (sel < 0) ? 0xFFFFFFFFu : (unsigned)sel;
        kk2[b] = krem;
    }
}

__global__ __launch_bounds__(1024) void k_h3(const unsigned* __restrict__ keys,
                                             const unsigned* __restrict__ selb1,
                                             const unsigned* __restrict__ selb2,
                                             unsigned* __restrict__ h3)
{
    __shared__ unsigned hist[1024];
    const int b = blockIdx.y, tid = threadIdx.x;
    hist[tid] = 0;
    __syncthreads();
    const unsigned top = (selb1[b] << 10) | selb2[b];
    const size_t base = (size_t)b * PP + (size_t)blockIdx.x * 32768;
    for (int j = 0; j < 32; j++) {
        unsigned key = keys[base + j * 1024 + tid];
        if ((key >> 10) == top) atomicAdd(&hist[key & 1023u], 1u);
    }
    __syncthreads();
    unsigned c = hist[tid];
    if (c) atomicAdd(&h3[b * 1024 + tid], c);
}

__global__ __launch_bounds__(256) void k_scan3(const unsigned* __restrict__ h3,
                                               const int* __restrict__ kk2,
                                               const unsigned* __restrict__ selb1,
                                               const unsigned* __restrict__ selb2,
                                               unsigned* __restrict__ Kstar,
                                               int* __restrict__ needeq)
{
    const int b = blockIdx.x;
    int sel, krem;
    find_kth<1024>(h3 + b * 1024, kk2[b], &sel, &krem);
    if (threadIdx.x == 0) {
        if (sel < 0) { Kstar[b] = 0xFFFFFFFFu; needeq[b] = 0; }
        else {
            Kstar[b] = (selb1[b] << 20) | (selb2[b] << 10) | (unsigned)sel;
            needeq[b] = krem;
        }
    }
}

// grid (16, BB) x 1024 threads, 8 keys/thread
__global__ __launch_bounds__(1024) void k_neg(const unsigned* __restrict__ keys,
                                              const unsigned* __restrict__ Kstar,
                                              float* __restrict__ negsum)
{
    __shared__ float sred[16];
    const int b = blockIdx.y, tid = threadIdx.x;
    const unsigned K = Kstar[b];
    const size_t base = (size_t)b * PP + (size_t)blockIdx.x * 8192;
    float v = 0.f;
#pragma unroll
    for (int j = 0; j < 8; j++) {
        unsigned key = keys[base + j * 1024 + tid];
        if (key > K) v += __uint_as_float(key);
    }
    for (int o = 32; o; o >>= 1) v += __shfl_xor(v, o);
    if ((tid & 63) == 0) sred[tid >> 6] = v;
    __syncthreads();
    if (tid == 0) {
        float s = 0.f;
        for (int w = 0; w < 16; w++) s += sred[w];
        if (s != 0.f) atomicAdd(&negsum[b], s);
    }
}

__global__ void k_final(const int* __restrict__ npos_r, const int* __restrict__ kimg,
                        const float* __restrict__ poscls_r, const float* __restrict__ negsum,
                        const float* __restrict__ locsum_r, const unsigned* __restrict__ Kstar,
                        const int* __restrict__ needeq, float* __restrict__ out)
{
    if (threadIdx.x == 0 && blockIdx.x == 0) {
        int npt = 0; long long maskc = 0; float clsnum = 0.f, locnum = 0.f;
        for (int b = 0; b < BB; b++) {
            int nb = 0; float pc = 0.f, lc = 0.f;
            for (int r = 0; r < 8; r++) {
                nb += npos_r[r * BB + b];
                pc += poscls_r[r * BB + b];
                lc += locsum_r[r * BB + b];
            }
            npt += nb;
            maskc += (long long)nb + kimg[b];
            float add = (needeq[b] > 0) ? needeq[b] * __uint_as_float(Kstar[b]) : 0.f;
            clsnum += pc + negsum[b] + add;
            locnum += lc;
        }
        float denom_loc = (float)((4 * npt > 1) ? 4 * npt : 1);
        float denom_cls = (float)((maskc > 1) ? maskc : 1);
        float loss_loc = locnum / denom_loc;
        float loss_cls = clsnum / denom_cls;
        float loss = (loss_cls + loss_loc) / (float)npt;
        out[0] = loss; out[1] = loss_loc; out[2] = loss_cls;
    }
}

extern "C" void kernel_launch(void* const* d_in, const int* in_sizes, int n_in,
                              void* d_out, int out_size, void* d_ws, size_t ws_size,
                              hipStream_t stream)
{
    const float* loc_preds = (const float*)d_in[0];
    const float* cls_preds = (const float*)d_in[1];
    const float* priorbox  = (const float*)d_in[2];
    const float* targets   = (const float*)d_in[3];
    float* out = (float*)d_out;

    char* ws = (char*)d_ws;
    unsigned long long* bestpk = (unsigned long long*)(ws + OFF_BESTPK);
    unsigned* h1     = (unsigned*)(ws + OFF_H1);
    unsigned* h2     = (unsigned*)(ws + OFF_H2);
    unsigned* h3     = (unsigned*)(ws + OFF_H3);
    int*      npos_r = (int*)(ws + OFF_NPOSR);
    float*    pcr    = (float*)(ws + OFF_PCR);
    float*    locr   = (float*)(ws + OFF_LOCR);
    float*    negsum = (float*)(ws + OFF_NEGS);
    int*      kimg   = (int*)(ws + OFF_KIMG);
    unsigned* selb1  = (unsigned*)(ws + OFF_SELB1);
    int*      kk1    = (int*)(ws + OFF_KK1);
    unsigned* selb2  = (unsigned*)(ws + OFF_SELB2);
    int*      kk2    = (int*)(ws + OFF_KK2);
    unsigned* Kstar  = (unsigned*)(ws + OFF_KSTAR);
    int*      needeq = (int*)(ws + OFF_NEEDEQ);
    unsigned* keys   = (unsigned*)(ws + OFF_KEYS);
    float*    bto    = (float*)(ws + OFF_BTO);
    unsigned char* bti = (unsigned char*)(ws + OFF_BTI);

    hipMemsetAsync(d_ws, 0, ZERO_BYTES, stream);

    k_match<<<dim3(PP / 2048, BB), 256, 0, stream>>>(priorbox, targets, bestpk, bto, bti);
    k_decode<<<BB, 64, 0, stream>>>(bestpk, bto, bti);
    k_loss<<<dim3(PP / 2048, BB), 256, 0, stream>>>(loc_preds, cls_preds, priorbox, targets,
                                                    bto, bti, keys, npos_r, pcr, locr);
    k_hist1<<<dim3(16, BB), 1024, 0, stream>>>(keys, h1);
    k_scan1<<<BB, 256, 0, stream>>>(h1, npos_r, kimg, selb1, kk1);
    k_h2<<<dim3(4, BB), 1024, 0, stream>>>(keys, selb1, h2);
    k_scan2<<<BB, 256, 0, stream>>>(h2, kk1, selb2, kk2);
    k_h3<<<dim3(4, BB), 1024, 0, stream>>>(keys, selb1, selb2, h3);
    k_scan3<<<BB, 256, 0, stream>>>(h3, kk2, selb1, selb2, Kstar, needeq);
    k_neg<<<dim3(16, BB), 1024, 0, stream>>>(keys, Kstar, negsum);
    k_final<<<1, 64, 0, stream>>>(npos_r, kimg, pcr, negsum, locr, Kstar, needeq, out);
}

// Round 3
// 189.383 us; speedup vs baseline: 5.2971x; 1.0389x over previous
//
#include <hip/hip_runtime.h>

#define BB 16
#define PP 131072
#define GG 64
#define THRESH 0.35f

// ---------------- workspace layout (bytes) ----------------
#define OFF_BESTPK   0         // u64[BB*GG]     8192
#define OFF_H1       8192      // u32[BB*4096]   262144
#define OFF_H2       270336    // u32[BB*1024]   65536
#define OFF_H3       335872    // u32[BB*1024]   65536
#define OFF_NPOSR    401408    // i32[16][BB]    1024
#define OFF_PCR      402432    // f32[16][BB]    1024
#define OFF_LOCR     403456    // f32[16][BB]    1024
#define OFF_NEGS     404480    // f32[BB]        64
#define OFF_KIMG     404544    // i32[BB]
#define OFF_SELB1    404608    // u32[BB]
#define OFF_KK1      404672    // i32[BB]
#define OFF_SELB2    404736    // u32[BB]
#define OFF_KK2      404800    // i32[BB]
#define OFF_KSTAR    404864    // u32[BB]
#define OFF_NEEDEQ   404928    // i32[BB]
#define ZERO_BYTES   404992
#define OFF_KEYS     404992    // u32[BB*PP]  8388608
#define OFF_BTO      8793600   // f32[BB*PP]  8388608
#define OFF_BTI      17182208  // u8 [BB*PP]  2097152

// ---------------- match kernel ----------------
// grid (PP/2048, BB), block 256; each thread: 8 priors (strided by 256) x 64 gts.
// launch_bounds(256,1): unlock VGPR budget so prior corners/areas stay resident
// (at 48 VGPRs the compiler rematerialized them per g-iteration -> 2.7x inst bloat).
__global__ __launch_bounds__(256, 1) void k_match(
    const float* __restrict__ priorbox, const float* __restrict__ targets,
    unsigned long long* __restrict__ bestpk, float* __restrict__ bto,
    unsigned char* __restrict__ bti)
{
    __shared__ float gx1[GG], gy1[GG], gx2[GG], gy2[GG], gar[GG];
    __shared__ unsigned long long sbest[GG];
    const int b = blockIdx.y;
    const int tid = threadIdx.x;
    if (tid < GG) {
        const float* t = targets + (size_t)(b * GG + tid) * 5;
        float x1 = t[1], y1 = t[0], x2 = t[3], y2 = t[2];  // gts = t[[1,0,3,2]]
        gx1[tid] = x1; gy1[tid] = y1; gx2[tid] = x2; gy2[tid] = y2;
        gar[tid] = (x2 - x1) * (y2 - y1);
        sbest[tid] = 0ull;
    }
    __syncthreads();

    const int pbase = blockIdx.x * 2048 + tid;
    float px1[8], py1[8], px2[8], py2[8], par[8];
    unsigned long long notp[8];
#pragma unroll
    for (int j = 0; j < 8; j++) {
        float4 pr = *reinterpret_cast<const float4*>(priorbox + (size_t)(pbase + j * 256) * 4);
        float hx = 0.5f * pr.z, hy = 0.5f * pr.w;
        px1[j] = pr.x - hx; py1[j] = pr.y - hy;
        px2[j] = pr.x + hx; py2[j] = pr.y + hy;
        par[j] = (px2[j] - px1[j]) * (py2[j] - py1[j]);
        notp[j] = (unsigned long long)(~(unsigned)(pbase + j * 256));
    }

    float bv[8] = {-1.f, -1.f, -1.f, -1.f, -1.f, -1.f, -1.f, -1.f};
    int   bg[8] = {0, 0, 0, 0, 0, 0, 0, 0};

    for (int r = 0; r < GG; r++) {
        const int g = (tid + r) & 63;                // 64 lanes -> 64 distinct g
        const float ax1 = gx1[g], ay1 = gy1[g], ax2 = gx2[g], ay2 = gy2[g], aar = gar[g];
        unsigned long long cand = 0ull;
#pragma unroll
        for (int j = 0; j < 8; j++) {
            float w = fminf(ax2, px2[j]) - fmaxf(ax1, px1[j]);
            float h = fminf(ay2, py2[j]) - fmaxf(ay1, py1[j]);
            w = fmaxf(w, 0.f); h = fmaxf(h, 0.f);
            float inter = w * h;
            float v = inter * __builtin_amdgcn_rcpf(aar + par[j] - inter);
            if (v > bv[j]) { bv[j] = v; bg[j] = g; }   // ties only at v==0 (negs) -> harmless
            // per-g argmax over p: (iou_bits, ~p) -> max iou, then min p
            unsigned long long pk =
                (((unsigned long long)__float_as_uint(v)) << 32) | notp[j];
            cand = cand > pk ? cand : pk;
        }
        atomicMax(&sbest[g], cand);
    }

#pragma unroll
    for (int j = 0; j < 8; j++) {
        const int p = pbase + j * 256;
        bto[(size_t)b * PP + p] = bv[j];
        bti[(size_t)b * PP + p] = (unsigned char)bg[j];
    }

    __syncthreads();
    if (tid < GG) atomicMax(&bestpk[b * GG + tid], sbest[tid]);
}

// ---------------- decode best priors + override ----------------
// grid BB blocks x 64 threads; serial g-loop => later g wins on duplicate priors
__global__ void k_decode(const unsigned long long* __restrict__ bestpk,
                         float* __restrict__ bto, unsigned char* __restrict__ bti)
{
    __shared__ unsigned long long spk[GG];
    const int b = blockIdx.x;
    spk[threadIdx.x] = bestpk[b * GG + threadIdx.x];
    __syncthreads();
    if (threadIdx.x == 0) {
        for (int g = 0; g < GG; g++) {
            unsigned p = ~((unsigned)(spk[g] & 0xFFFFFFFFull));
            bto[(size_t)b * PP + p] = 2.0f;
            bti[(size_t)b * PP + p] = (unsigned char)g;
        }
    }
}

// ---------------- loss pass (keys + pos sums + h1 histogram) ----------------
// grid (PP/8192, BB) = (16,BB), block 1024, 8 priors/thread strided by 1024
__global__ __launch_bounds__(1024) void k_loss(
    const float* __restrict__ loc_preds, const float* __restrict__ cls_preds,
    const float* __restrict__ priorbox, const float* __restrict__ targets,
    const float* __restrict__ bto, const unsigned char* __restrict__ bti,
    unsigned* __restrict__ keys, unsigned* __restrict__ h1,
    int* __restrict__ npos_r, float* __restrict__ poscls_r, float* __restrict__ locsum_r)
{
    __shared__ float gx1[GG], gy1[GG], gx2[GG], gy2[GG], glab[GG];
    __shared__ unsigned hist[4096];
    __shared__ float sred[32];
    __shared__ int sredi[16];
    const int b = blockIdx.y;
    const int tid = threadIdx.x;
    for (int i = tid; i < 4096; i += 1024) hist[i] = 0;
    if (tid < GG) {
        const float* t = targets + (size_t)(b * GG + tid) * 5;
        gx1[tid] = t[1]; gy1[tid] = t[0]; gx2[tid] = t[3]; gy2[tid] = t[2];
        glab[tid] = t[4];
    }
    __syncthreads();

    const int pbase = blockIdx.x * 8192 + tid;
    float locpart = 0.f, clspart = 0.f; int cnt = 0;

#pragma unroll
    for (int j = 0; j < 8; j++) {
        const int p = pbase + j * 1024;
        const size_t ip = (size_t)b * PP + p;
        const float bv = bto[ip];
        const int g = bti[ip];
        const float2 cl = *reinterpret_cast<const float2*>(cls_preds + ip * 2);
        const float mx = fmaxf(cl.x, cl.y);
        const float lse = mx + log1pf(expf(fminf(cl.x, cl.y) - mx));
        const float conf = (bv < THRESH) ? 0.f : glab[g];
        unsigned key = 0u;
        if (conf > 0.f) {
            float gathered = (((int)conf) == 0) ? cl.x : cl.y;
            clspart += lse - gathered;
            cnt++;
            float4 pr = *reinterpret_cast<const float4*>(priorbox + (size_t)p * 4);
            float mx1 = gx1[g], my1 = gy1[g], mx2 = gx2[g], my2 = gy2[g];
            float gcx = ((mx1 + mx2) * 0.5f - pr.x) / (0.1f * pr.z);
            float gcy = ((my1 + my2) * 0.5f - pr.y) / (0.1f * pr.w);
            float gw = logf((mx2 - mx1) / pr.z) / 0.2f;
            float gh = logf((my2 - my1) / pr.w) / 0.2f;
            float4 lp = *reinterpret_cast<const float4*>(loc_preds + ip * 4);
            float d0 = lp.x - gcx, d1 = lp.y - gcy, d2 = lp.z - gw, d3 = lp.w - gh;
            float a0 = fabsf(d0), a1 = fabsf(d1), a2 = fabsf(d2), a3 = fabsf(d3);
            locpart += ((a0 < 1.f) ? 0.5f * d0 * d0 : a0 - 0.5f)
                     + ((a1 < 1.f) ? 0.5f * d1 * d1 : a1 - 0.5f)
                     + ((a2 < 1.f) ? 0.5f * d2 * d2 : a2 - 0.5f)
                     + ((a3 < 1.f) ? 0.5f * d3 * d3 : a3 - 0.5f);
        } else {
            key = __float_as_uint(lse - cl.x);       // loss_c > 0 strictly for negs
        }
        keys[ip] = key;
        atomicAdd(&hist[key >> 20], 1u);
    }

    for (int o = 32; o; o >>= 1) {
        locpart += __shfl_xor(locpart, o);
        clspart += __shfl_xor(clspart, o);
        cnt     += __shfl_xor(cnt, o);
    }
    const int w = tid >> 6;
    if ((tid & 63) == 0) { sred[w] = locpart; sred[16 + w] = clspart; sredi[w] = cnt; }
    __syncthreads();
    if (tid == 0) {
        float l = 0.f, c = 0.f; int n = 0;
        for (int i = 0; i < 16; i++) { l += sred[i]; c += sred[16 + i]; n += sredi[i]; }
        const int rep = blockIdx.x * BB + b;
        if (n)        atomicAdd(&npos_r[rep], n);
        if (c != 0.f) atomicAdd(&poscls_r[rep], c);
        if (l != 0.f) atomicAdd(&locsum_r[rep], l);
    }
    __syncthreads();
    for (int i = tid; i < 4096; i += 1024) {
        unsigned cc = hist[i];
        if (cc) atomicAdd(&h1[b * 4096 + i], cc);
    }
}

// ---------------- descending k-th finder ----------------
template <int NBINS>
__device__ void find_kth(const unsigned* __restrict__ h, int k, int* sel, int* krem)
{
    constexpr int PER = NBINS / 256;
    __shared__ unsigned part[256];
    __shared__ int res[2];
    const int tid = threadIdx.x;
    unsigned s = 0;
#pragma unroll
    for (int i = 0; i < PER; i++) s += h[NBINS - 1 - (tid * PER + i)];
    part[tid] = s;
    __syncthreads();
    if (tid == 0) {
        int fsel = -1, fk = 0;
        if (k > 0) {
            unsigned run = 0;
            for (int t = 0; t < 256; t++) {
                if (run + part[t] >= (unsigned)k) {
                    for (int i = 0; i < PER; i++) {
                        int bin = NBINS - 1 - (t * PER + i);
                        unsigned hv = h[bin];
                        run += hv;
                        if (run >= (unsigned)k) { fsel = bin; fk = k - (int)(run - hv); break; }
                    }
                    break;
                }
                run += part[t];
            }
        }
        res[0] = fsel; res[1] = fk;
    }
    __syncthreads();
    *sel = res[0]; *krem = res[1];
}

__global__ __launch_bounds__(256) void k_scan1(const unsigned* __restrict__ h1,
                                               const int* __restrict__ npos_r,
                                               int* __restrict__ kimg,
                                               unsigned* __restrict__ selb1,
                                               int* __restrict__ kk1)
{
    const int b = blockIdx.x;
    int np = 0;
    for (int r = 0; r < 16; r++) np += npos_r[r * BB + b];
    const int k = min(3 * np, PP - 1);
    int sel, krem;
    find_kth<4096>(h1 + b * 4096, k, &sel, &krem);
    if (threadIdx.x == 0) {
        kimg[b] = k;
        selb1[b] = (sel < 0) ? 0xFFFFFFFFu : (unsigned)sel;
        kk1[b] = krem;
    }
}

// grid (4, BB) x 1024 threads, 32 keys/thread
__global__ __launch_bounds__(1024) void k_h2(const unsigned* __restrict__ keys,
                                             const unsigned* __restrict__ selb1,
                                             unsigned* __restrict__ h2)
{
    __shared__ unsigned hist[1024];
    const int b = blockIdx.y, tid = threadIdx.x;
    hist[tid] = 0;
    __syncthreads();
    const unsigned s = selb1[b];
    const size_t base = (size_t)b * PP + (size_t)blockIdx.x * 32768;
    for (int j = 0; j < 32; j++) {
        unsigned key = keys[base + j * 1024 + tid];
        if ((key >> 20) == s) atomicAdd(&hist[(key >> 10) & 1023u], 1u);
    }
    __syncthreads();
    unsigned c = hist[tid];
    if (c) atomicAdd(&h2[b * 1024 + tid], c);
}

__global__ __launch_bounds__(256) void k_scan2(const unsigned* __restrict__ h2,
                                               const int* __restrict__ kk1,
                                               unsigned* __restrict__ selb2,
                                               int* __restrict__ kk2)
{
    const int b = blockIdx.x;
    int sel, krem;
    find_kth<1024>(h2 + b * 1024, kk1[b], &sel, &krem);
    if (threadIdx.x == 0) {
        selb2[b] = (sel < 0) ? 0xFFFFFFFFu : (unsigned)sel;
        kk2[b] = krem;
    }
}

__global__ __launch_bounds__(1024) void k_h3(const unsigned* __restrict__ keys,
                                             const unsigned* __restrict__ selb1,
                                             const unsigned* __restrict__ selb2,
                                             unsigned* __restrict__ h3)
{
    __shared__ unsigned hist[1024];
    const int b = blockIdx.y, tid = threadIdx.x;
    hist[tid] = 0;
    __syncthreads();
    const unsigned top = (selb1[b] << 10) | selb2[b];
    const size_t base = (size_t)b * PP + (size_t)blockIdx.x * 32768;
    for (int j = 0; j < 32; j++) {
        unsigned key = keys[base + j * 1024 + tid];
        if ((key >> 10) == top) atomicAdd(&hist[key & 1023u], 1u);
    }
    __syncthreads();
    unsigned c = hist[tid];
    if (c) atomicAdd(&h3[b * 1024 + tid], c);
}

__global__ __launch_bounds__(256) void k_scan3(const unsigned* __restrict__ h3,
                                               const int* __restrict__ kk2,
                                               const unsigned* __restrict__ selb1,
                                               const unsigned* __restrict__ selb2,
                                               unsigned* __restrict__ Kstar,
                                               int* __restrict__ needeq)
{
    const int b = blockIdx.x;
    int sel, krem;
    find_kth<1024>(h3 + b * 1024, kk2[b], &sel, &krem);
    if (threadIdx.x == 0) {
        if (sel < 0) { Kstar[b] = 0xFFFFFFFFu; needeq[b] = 0; }
        else {
            Kstar[b] = (selb1[b] << 20) | (selb2[b] << 10) | (unsigned)sel;
            needeq[b] = krem;
        }
    }
}

// grid (16, BB) x 1024 threads, 8 keys/thread
__global__ __launch_bounds__(1024) void k_neg(const unsigned* __restrict__ keys,
                                              const unsigned* __restrict__ Kstar,
                                              float* __restrict__ negsum)
{
    __shared__ float sred[16];
    const int b = blockIdx.y, tid = threadIdx.x;
    const unsigned K = Kstar[b];
    const size_t base = (size_t)b * PP + (size_t)blockIdx.x * 8192;
    float v = 0.f;
#pragma unroll
    for (int j = 0; j < 8; j++) {
        unsigned key = keys[base + j * 1024 + tid];
        if (key > K) v += __uint_as_float(key);
    }
    for (int o = 32; o; o >>= 1) v += __shfl_xor(v, o);
    if ((tid & 63) == 0) sred[tid >> 6] = v;
    __syncthreads();
    if (tid == 0) {
        float s = 0.f;
        for (int w = 0; w < 16; w++) s += sred[w];
        if (s != 0.f) atomicAdd(&negsum[b], s);
    }
}

__global__ void k_final(const int* __restrict__ npos_r, const int* __restrict__ kimg,
                        const float* __restrict__ poscls_r, const float* __restrict__ negsum,
                        const float* __restrict__ locsum_r, const unsigned* __restrict__ Kstar,
                        const int* __restrict__ needeq, float* __restrict__ out)
{
    if (threadIdx.x == 0 && blockIdx.x == 0) {
        int npt = 0; long long maskc = 0; float clsnum = 0.f, locnum = 0.f;
        for (int b = 0; b < BB; b++) {
            int nb = 0; float pc = 0.f, lc = 0.f;
            for (int r = 0; r < 16; r++) {
                nb += npos_r[r * BB + b];
                pc += poscls_r[r * BB + b];
                lc += locsum_r[r * BB + b];
            }
            npt += nb;
            maskc += (long long)nb + kimg[b];
            float add = (needeq[b] > 0) ? needeq[b] * __uint_as_float(Kstar[b]) : 0.f;
            clsnum += pc + negsum[b] + add;
            locnum += lc;
        }
        float denom_loc = (float)((4 * npt > 1) ? 4 * npt : 1);
        float denom_cls = (float)((maskc > 1) ? maskc : 1);
        float loss_loc = locnum / denom_loc;
        float loss_cls = clsnum / denom_cls;
        float loss = (loss_cls + loss_loc) / (float)npt;
        out[0] = loss; out[1] = loss_loc; out[2] = loss_cls;
    }
}

extern "C" void kernel_launch(void* const* d_in, const int* in_sizes, int n_in,
                              void* d_out, int out_size, void* d_ws, size_t ws_size,
                              hipStream_t stream)
{
    const float* loc_preds = (const float*)d_in[0];
    const float* cls_preds = (const float*)d_in[1];
    const float* priorbox  = (const float*)d_in[2];
    const float* targets   = (const float*)d_in[3];
    float* out = (float*)d_out;

    char* ws = (char*)d_ws;
    unsigned long long* bestpk = (unsigned long long*)(ws + OFF_BESTPK);
    unsigned* h1     = (unsigned*)(ws + OFF_H1);
    unsigned* h2     = (unsigned*)(ws + OFF_H2);
    unsigned* h3     = (unsigned*)(ws + OFF_H3);
    int*      npos_r = (int*)(ws + OFF_NPOSR);
    float*    pcr    = (float*)(ws + OFF_PCR);
    float*    locr   = (float*)(ws + OFF_LOCR);
    float*    negsum = (float*)(ws + OFF_NEGS);
    int*      kimg   = (int*)(ws + OFF_KIMG);
    unsigned* selb1  = (unsigned*)(ws + OFF_SELB1);
    int*      kk1    = (int*)(ws + OFF_KK1);
    unsigned* selb2  = (unsigned*)(ws + OFF_SELB2);
    int*      kk2    = (int*)(ws + OFF_KK2);
    unsigned* Kstar  = (unsigned*)(ws + OFF_KSTAR);
    int*      needeq = (int*)(ws + OFF_NEEDEQ);
    unsigned* keys   = (unsigned*)(ws + OFF_KEYS);
    float*    bto    = (float*)(ws + OFF_BTO);
    unsigned char* bti = (unsigned char*)(ws + OFF_BTI);

    hipMemsetAsync(d_ws, 0, ZERO_BYTES, stream);

    k_match<<<dim3(PP / 2048, BB), 256, 0, stream>>>(priorbox, targets, bestpk, bto, bti);
    k_decode<<<BB, 64, 0, stream>>>(bestpk, bto, bti);
    k_loss<<<dim3(16, BB), 1024, 0, stream>>>(loc_preds, cls_preds, priorbox, targets,
                                              bto, bti, keys, h1, npos_r, pcr, locr);
    k_scan1<<<BB, 256, 0, stream>>>(h1, npos_r, kimg, selb1, kk1);
    k_h2<<<dim3(4, BB), 1024, 0, stream>>>(keys, selb1, h2);
    k_scan2<<<BB, 256, 0, stream>>>(h2, kk1, selb2, kk2);
    k_h3<<<dim3(4, BB), 1024, 0, stream>>>(keys, selb1, selb2, h3);
    k_scan3<<<BB, 256, 0, stream>>>(h3, kk2, selb1, selb2, Kstar, needeq);
    k_neg<<<dim3(16, BB), 1024, 0, stream>>>(keys, Kstar, negsum);
    k_final<<<1, 64, 0, stream>>>(npos_r, kimg, pcr, negsum, locr, Kstar, needeq, out);
}

// Round 4
// 112.812 us; speedup vs baseline: 8.8925x; 1.6788x over previous
//
#include <hip/hip_runtime.h>

#define BB 16
#define PP 131072
#define GG 64
#define THRESH 0.35f
#define RMAX 0.086f          // max prior half-extent 0.085 + float-slop margin
#define NCELL 64             // 64x64 spatial grid, cell = 1/64

// ---------------- workspace layout (bytes) ----------------
#define OFF_BESTPK   0         // u64[BB*GG]     8192
#define OFF_H1       8192      // u32[BB*4096]   262144
#define OFF_H2       270336    // u32[BB*1024]   65536
#define OFF_H3       335872    // u32[BB*1024]   65536
#define OFF_NPOSR    401408    // i32[16][BB]    1024
#define OFF_PCR      402432    // f32[16][BB]    1024
#define OFF_LOCR     403456    // f32[16][BB]    1024
#define OFF_NEGS     404480    // f32[BB]        64
#define OFF_KIMG     404544    // i32[BB]        64
#define OFF_KSTAR    404608    // u32[BB]        64
#define OFF_NEEDEQ   404672    // i32[BB]        64
#define ZERO_BYTES   404736
#define OFF_KEYS     404736    // u32[BB*PP]     8388608
#define OFF_BTO      8793344   // f32[BB*PP]     8388608
#define OFF_BTI      17181952  // u8 [BB*PP]     2097152
#define OFF_MASK     19279104  // u64[BB*4096]   524288   (total ~19.8 MB)

// ---------------- gt-bitmask grid build ----------------
// grid (16, BB) x 256: one thread per cell. Cell includes gt g iff a prior
// centered anywhere in the cell could overlap gt g (gt box expanded by RMAX).
__global__ __launch_bounds__(256) void k_build_mask(
    const float* __restrict__ targets, unsigned long long* __restrict__ gmask)
{
    __shared__ float sx1[GG], sy1[GG], sx2[GG], sy2[GG];
    const int b = blockIdx.y;
    const int tid = threadIdx.x;
    if (tid < GG) {
        const float* t = targets + (size_t)(b * GG + tid) * 5;
        sx1[tid] = t[1] - RMAX; sy1[tid] = t[0] - RMAX;   // gts = t[[1,0,3,2]]
        sx2[tid] = t[3] + RMAX; sy2[tid] = t[2] + RMAX;
    }
    __syncthreads();
    const int cell = blockIdx.x * 256 + tid;
    const int cxi = cell & (NCELL - 1), cyi = cell >> 6;
    const float cx0 = cxi * (1.f / NCELL), cx1 = cx0 + (1.f / NCELL);
    const float cy0 = cyi * (1.f / NCELL), cy1 = cy0 + (1.f / NCELL);
    unsigned long long m = 0ull;
    for (int g = 0; g < GG; g++) {
        bool in = (sx1[g] < cx1) && (sx2[g] > cx0) && (sy1[g] < cy1) && (sy2[g] > cy0);
        m |= in ? (1ull << g) : 0ull;
    }
    gmask[(size_t)b * 4096 + cell] = m;
}

// ---------------- match kernel (mask-pruned) ----------------
// grid (PP/2048, BB), block 256; 8 priors/thread; per prior iterate only the
// ~4 gts whose expanded box covers the prior's cell. Zero-IoU pairs are
// irrelevant: bti matters only when bto>=THRESH, and each gt's best prior
// has IoU>0 with probability 1.
__global__ __launch_bounds__(256) void k_match(
    const float* __restrict__ priorbox, const float* __restrict__ targets,
    const unsigned long long* __restrict__ gmask,
    unsigned long long* __restrict__ bestpk, float* __restrict__ bto,
    unsigned char* __restrict__ bti)
{
    __shared__ float4 gxy[GG];
    __shared__ float gar[GG];
    __shared__ unsigned long long sbest[GG];
    const int b = blockIdx.y;
    const int tid = threadIdx.x;
    if (tid < GG) {
        const float* t = targets + (size_t)(b * GG + tid) * 5;
        float x1 = t[1], y1 = t[0], x2 = t[3], y2 = t[2];
        gxy[tid] = make_float4(x1, y1, x2, y2);
        gar[tid] = (x2 - x1) * (y2 - y1);
        sbest[tid] = 0ull;
    }
    __syncthreads();

    const int pbase = blockIdx.x * 2048 + tid;
    const unsigned long long* mrow = gmask + (size_t)b * 4096;

#pragma unroll
    for (int j = 0; j < 8; j++) {
        const int p = pbase + j * 256;
        float4 pr = *reinterpret_cast<const float4*>(priorbox + (size_t)p * 4);
        float hx = 0.5f * pr.z, hy = 0.5f * pr.w;
        float px1 = pr.x - hx, py1 = pr.y - hy;
        float px2 = pr.x + hx, py2 = pr.y + hy;
        float par = (px2 - px1) * (py2 - py1);          // matches reference rounding
        int cx = (int)(pr.x * (float)NCELL); cx = cx > 63 ? 63 : cx;
        int cy = (int)(pr.y * (float)NCELL); cy = cy > 63 ? 63 : cy;
        unsigned long long m = mrow[cy * NCELL + cx];
        const unsigned long long notp = (unsigned long long)(~(unsigned)p);
        float bv = -1.f; int bg = 0;
        while (m) {
            const int g = __ffsll((unsigned long long)m) - 1;   // ascending g => first-max tiebreak
            m &= m - 1;
            float4 a = gxy[g];
            float w = fminf(a.z, px2) - fmaxf(a.x, px1);
            float h = fminf(a.w, py2) - fmaxf(a.y, py1);
            w = fmaxf(w, 0.f); h = fmaxf(h, 0.f);
            float inter = w * h;
            float v = inter * __builtin_amdgcn_rcpf(gar[g] + par - inter);
            if (v > bv) { bv = v; bg = g; }
            if (v > 0.f) {
                unsigned long long pk =
                    (((unsigned long long)__float_as_uint(v)) << 32) | notp;
                atomicMax(&sbest[g], pk);
            }
        }
        bto[(size_t)b * PP + p] = bv;
        bti[(size_t)b * PP + p] = (unsigned char)bg;
    }

    __syncthreads();
    if (tid < GG) atomicMax(&bestpk[b * GG + tid], sbest[tid]);
}

// ---------------- decode best priors + override ----------------
__global__ void k_decode(const unsigned long long* __restrict__ bestpk,
                         float* __restrict__ bto, unsigned char* __restrict__ bti)
{
    __shared__ unsigned long long spk[GG];
    const int b = blockIdx.x;
    spk[threadIdx.x] = bestpk[b * GG + threadIdx.x];
    __syncthreads();
    if (threadIdx.x == 0) {
        for (int g = 0; g < GG; g++) {                    // serial: later g wins
            unsigned p = ~((unsigned)(spk[g] & 0xFFFFFFFFull));
            bto[(size_t)b * PP + p] = 2.0f;
            bti[(size_t)b * PP + p] = (unsigned char)g;
        }
    }
}

// ---------------- loss pass (keys + pos sums + h1 histogram) ----------------
// grid (16, BB), block 1024, 8 priors/thread strided by 1024
__global__ __launch_bounds__(1024) void k_loss(
    const float* __restrict__ loc_preds, const float* __restrict__ cls_preds,
    const float* __restrict__ priorbox, const float* __restrict__ targets,
    const float* __restrict__ bto, const unsigned char* __restrict__ bti,
    unsigned* __restrict__ keys, unsigned* __restrict__ h1,
    int* __restrict__ npos_r, float* __restrict__ poscls_r, float* __restrict__ locsum_r)
{
    __shared__ float gx1[GG], gy1[GG], gx2[GG], gy2[GG], glab[GG];
    __shared__ unsigned hist[4096];
    __shared__ float sred[32];
    __shared__ int sredi[16];
    const int b = blockIdx.y;
    const int tid = threadIdx.x;
    for (int i = tid; i < 4096; i += 1024) hist[i] = 0;
    if (tid < GG) {
        const float* t = targets + (size_t)(b * GG + tid) * 5;
        gx1[tid] = t[1]; gy1[tid] = t[0]; gx2[tid] = t[3]; gy2[tid] = t[2];
        glab[tid] = t[4];
    }
    __syncthreads();

    const int pbase = blockIdx.x * 8192 + tid;
    float locpart = 0.f, clspart = 0.f; int cnt = 0;

#pragma unroll
    for (int j = 0; j < 8; j++) {
        const int p = pbase + j * 1024;
        const size_t ip = (size_t)b * PP + p;
        const float bv = bto[ip];
        const int g = bti[ip];
        const float2 cl = *reinterpret_cast<const float2*>(cls_preds + ip * 2);
        const float mx = fmaxf(cl.x, cl.y);
        const float lse = mx + log1pf(expf(fminf(cl.x, cl.y) - mx));
        const float conf = (bv < THRESH) ? 0.f : glab[g];
        unsigned key = 0u;
        if (conf > 0.f) {
            float gathered = (((int)conf) == 0) ? cl.x : cl.y;
            clspart += lse - gathered;
            cnt++;
            float4 pr = *reinterpret_cast<const float4*>(priorbox + (size_t)p * 4);
            float mx1 = gx1[g], my1 = gy1[g], mx2 = gx2[g], my2 = gy2[g];
            float gcx = ((mx1 + mx2) * 0.5f - pr.x) / (0.1f * pr.z);
            float gcy = ((my1 + my2) * 0.5f - pr.y) / (0.1f * pr.w);
            float gw = logf((mx2 - mx1) / pr.z) / 0.2f;
            float gh = logf((my2 - my1) / pr.w) / 0.2f;
            float4 lp = *reinterpret_cast<const float4*>(loc_preds + ip * 4);
            float d0 = lp.x - gcx, d1 = lp.y - gcy, d2 = lp.z - gw, d3 = lp.w - gh;
            float a0 = fabsf(d0), a1 = fabsf(d1), a2 = fabsf(d2), a3 = fabsf(d3);
            locpart += ((a0 < 1.f) ? 0.5f * d0 * d0 : a0 - 0.5f)
                     + ((a1 < 1.f) ? 0.5f * d1 * d1 : a1 - 0.5f)
                     + ((a2 < 1.f) ? 0.5f * d2 * d2 : a2 - 0.5f)
                     + ((a3 < 1.f) ? 0.5f * d3 * d3 : a3 - 0.5f);
        } else {
            key = __float_as_uint(lse - cl.x);            // loss_c > 0 strictly for negs
        }
        keys[ip] = key;
        atomicAdd(&hist[key >> 20], 1u);
    }

    for (int o = 32; o; o >>= 1) {
        locpart += __shfl_xor(locpart, o);
        clspart += __shfl_xor(clspart, o);
        cnt     += __shfl_xor(cnt, o);
    }
    const int w = tid >> 6;
    if ((tid & 63) == 0) { sred[w] = locpart; sred[16 + w] = clspart; sredi[w] = cnt; }
    __syncthreads();
    if (tid == 0) {
        float l = 0.f, c = 0.f; int n = 0;
        for (int i = 0; i < 16; i++) { l += sred[i]; c += sred[16 + i]; n += sredi[i]; }
        const int rep = blockIdx.x * BB + b;
        if (n)        atomicAdd(&npos_r[rep], n);
        if (c != 0.f) atomicAdd(&poscls_r[rep], c);
        if (l != 0.f) atomicAdd(&locsum_r[rep], l);
    }
    __syncthreads();
    for (int i = tid; i < 4096; i += 1024) {
        unsigned cc = hist[i];
        if (cc) atomicAdd(&h1[b * 4096 + i], cc);
    }
}

// ---------------- parallel descending k-th finder (block of 1024) ----------------
template <int NBINS>
__device__ void find_kth_par(const unsigned* __restrict__ h, int k, int* sel, int* krem)
{
    constexpr int PER = NBINS / 1024;
    __shared__ unsigned wsum_[16];
    __shared__ int res_[2];
    const int tid = threadIdx.x, lane = tid & 63, wid = tid >> 6;
    __syncthreads();                         // protect LDS reuse across calls
    unsigned own[PER];
    unsigned s = 0;
#pragma unroll
    for (int i = 0; i < PER; i++) { own[i] = h[NBINS - 1 - (tid * PER + i)]; s += own[i]; }
    unsigned incl = s;
    for (int d = 1; d < 64; d <<= 1) {
        unsigned t = __shfl_up(incl, d);
        if (lane >= d) incl += t;
    }
    if (lane == 63) wsum_[wid] = incl;
    if (tid == 0) { res_[0] = -1; res_[1] = 0; }
    __syncthreads();
    unsigned woff = 0;
    for (int w = 0; w < 16; w++) woff += (w < wid) ? wsum_[w] : 0u;
    const unsigned texcl = woff + incl - s;
    if (k > 0 && texcl < (unsigned)k && texcl + s >= (unsigned)k) {
        unsigned run = texcl;
#pragma unroll
        for (int i = 0; i < PER; i++) {
            run += own[i];
            if (run >= (unsigned)k) {
                res_[0] = NBINS - 1 - (tid * PER + i);
                res_[1] = k - (int)(run - own[i]);
                break;
            }
        }
    }
    __syncthreads();
    *sel = res_[0]; *krem = res_[1];
}

// ---------------- pass 2: scan1 (redundant per block) + h2 build ----------------
// grid (4, BB) x 1024, 32 keys/thread
__global__ __launch_bounds__(1024) void k_sel2(
    const unsigned* __restrict__ keys, const unsigned* __restrict__ h1,
    const int* __restrict__ npos_r, unsigned* __restrict__ h2,
    int* __restrict__ kimg)
{
    __shared__ unsigned hist[1024];
    const int b = blockIdx.y, tid = threadIdx.x;
    hist[tid] = 0;
    int np = 0;
    for (int r = 0; r < 16; r++) np += npos_r[r * BB + b];
    const int k = min(3 * np, PP - 1);
    int sel, krem;
    find_kth_par<4096>(h1 + b * 4096, k, &sel, &krem);
    if (blockIdx.x == 0 && tid == 0) kimg[b] = k;
    const unsigned s = (unsigned)sel;                    // -1 -> matches nothing
    const size_t base = (size_t)b * PP + (size_t)blockIdx.x * 32768;
    for (int j = 0; j < 32; j++) {
        unsigned key = keys[base + j * 1024 + tid];
        if ((key >> 20) == s) atomicAdd(&hist[(key >> 10) & 1023u], 1u);
    }
    __syncthreads();
    unsigned c = hist[tid];
    if (c) atomicAdd(&h2[b * 1024 + tid], c);
}

// ---------------- pass 3: scan1+scan2 (redundant) + h3 build ----------------
__global__ __launch_bounds__(1024) void k_sel3(
    const unsigned* __restrict__ keys, const unsigned* __restrict__ h1,
    const unsigned* __restrict__ h2, const int* __restrict__ npos_r,
    unsigned* __restrict__ h3)
{
    __shared__ unsigned hist[1024];
    const int b = blockIdx.y, tid = threadIdx.x;
    hist[tid] = 0;
    int np = 0;
    for (int r = 0; r < 16; r++) np += npos_r[r * BB + b];
    const int k = min(3 * np, PP - 1);
    int sel1, kk1, sel2, kk2;
    find_kth_par<4096>(h1 + b * 4096, k, &sel1, &kk1);
    find_kth_par<1024>(h2 + b * 1024, kk1, &sel2, &kk2);
    const unsigned top = ((unsigned)sel1 << 10) | ((unsigned)sel2 & 1023u);
    const size_t base = (size_t)b * PP + (size_t)blockIdx.x * 32768;
    for (int j = 0; j < 32; j++) {
        unsigned key = keys[base + j * 1024 + tid];
        if ((key >> 10) == top) atomicAdd(&hist[key & 1023u], 1u);
    }
    __syncthreads();
    unsigned c = hist[tid];
    if (c) atomicAdd(&h3[b * 1024 + tid], c);
}

// ---------------- neg-sum: full scan chain (redundant) + selected-key sum ----------------
// grid (16, BB) x 1024, 8 keys/thread
__global__ __launch_bounds__(1024) void k_neg(
    const unsigned* __restrict__ keys, const unsigned* __restrict__ h1,
    const unsigned* __restrict__ h2, const unsigned* __restrict__ h3,
    const int* __restrict__ npos_r, float* __restrict__ negsum,
    unsigned* __restrict__ KstarA, int* __restrict__ needeqA)
{
    __shared__ float sred[16];
    const int b = blockIdx.y, tid = threadIdx.x;
    int np = 0;
    for (int r = 0; r < 16; r++) np += npos_r[r * BB + b];
    const int k = min(3 * np, PP - 1);
    int sel1, kk1, sel2, kk2, sel3, krem3;
    find_kth_par<4096>(h1 + b * 4096, k, &sel1, &kk1);
    find_kth_par<1024>(h2 + b * 1024, kk1, &sel2, &kk2);
    find_kth_par<1024>(h3 + b * 1024, kk2, &sel3, &krem3);
    unsigned Kstar; int needeq;
    if (sel3 < 0) { Kstar = 0xFFFFFFFFu; needeq = 0; }
    else {
        Kstar = ((unsigned)sel1 << 20) | ((unsigned)sel2 << 10) | (unsigned)sel3;
        needeq = krem3;
    }
    if (blockIdx.x == 0 && tid == 0) { KstarA[b] = Kstar; needeqA[b] = needeq; }
    const size_t base = (size_t)b * PP + (size_t)blockIdx.x * 8192;
    float v = 0.f;
#pragma unroll
    for (int j = 0; j < 8; j++) {
        unsigned key = keys[base + j * 1024 + tid];
        if (key > Kstar) v += __uint_as_float(key);
    }
    for (int o = 32; o; o >>= 1) v += __shfl_xor(v, o);
    if ((tid & 63) == 0) sred[tid >> 6] = v;
    __syncthreads();
    if (tid == 0) {
        float s2 = 0.f;
        for (int w2 = 0; w2 < 16; w2++) s2 += sred[w2];
        if (s2 != 0.f) atomicAdd(&negsum[b], s2);
    }
}

__global__ void k_final(const int* __restrict__ npos_r, const int* __restrict__ kimg,
                        const float* __restrict__ poscls_r, const float* __restrict__ negsum,
                        const float* __restrict__ locsum_r, const unsigned* __restrict__ Kstar,
                        const int* __restrict__ needeq, float* __restrict__ out)
{
    if (threadIdx.x == 0 && blockIdx.x == 0) {
        int npt = 0; long long maskc = 0; float clsnum = 0.f, locnum = 0.f;
        for (int b = 0; b < BB; b++) {
            int nb = 0; float pc = 0.f, lc = 0.f;
            for (int r = 0; r < 16; r++) {
                nb += npos_r[r * BB + b];
                pc += poscls_r[r * BB + b];
                lc += locsum_r[r * BB + b];
            }
            npt += nb;
            maskc += (long long)nb + kimg[b];
            float add = (needeq[b] > 0) ? needeq[b] * __uint_as_float(Kstar[b]) : 0.f;
            clsnum += pc + negsum[b] + add;
            locnum += lc;
        }
        float denom_loc = (float)((4 * npt > 1) ? 4 * npt : 1);
        float denom_cls = (float)((maskc > 1) ? maskc : 1);
        float loss_loc = locnum / denom_loc;
        float loss_cls = clsnum / denom_cls;
        float loss = (loss_cls + loss_loc) / (float)npt;
        out[0] = loss; out[1] = loss_loc; out[2] = loss_cls;
    }
}

extern "C" void kernel_launch(void* const* d_in, const int* in_sizes, int n_in,
                              void* d_out, int out_size, void* d_ws, size_t ws_size,
                              hipStream_t stream)
{
    const float* loc_preds = (const float*)d_in[0];
    const float* cls_preds = (const float*)d_in[1];
    const float* priorbox  = (const float*)d_in[2];
    const float* targets   = (const float*)d_in[3];
    float* out = (float*)d_out;

    char* ws = (char*)d_ws;
    unsigned long long* bestpk = (unsigned long long*)(ws + OFF_BESTPK);
    unsigned* h1     = (unsigned*)(ws + OFF_H1);
    unsigned* h2     = (unsigned*)(ws + OFF_H2);
    unsigned* h3     = (unsigned*)(ws + OFF_H3);
    int*      npos_r = (int*)(ws + OFF_NPOSR);
    float*    pcr    = (float*)(ws + OFF_PCR);
    float*    locr   = (float*)(ws + OFF_LOCR);
    float*    negsum = (float*)(ws + OFF_NEGS);
    int*      kimg   = (int*)(ws + OFF_KIMG);
    unsigned* Kstar  = (unsigned*)(ws + OFF_KSTAR);
    int*      needeq = (int*)(ws + OFF_NEEDEQ);
    unsigned* keys   = (unsigned*)(ws + OFF_KEYS);
    float*    bto    = (float*)(ws + OFF_BTO);
    unsigned char* bti = (unsigned char*)(ws + OFF_BTI);
    unsigned long long* gmask = (unsigned long long*)(ws + OFF_MASK);

    hipMemsetAsync(d_ws, 0, ZERO_BYTES, stream);

    k_build_mask<<<dim3(16, BB), 256, 0, stream>>>(targets, gmask);
    k_match<<<dim3(PP / 2048, BB), 256, 0, stream>>>(priorbox, targets, gmask,
                                                     bestpk, bto, bti);
    k_decode<<<BB, 64, 0, stream>>>(bestpk, bto, bti);
    k_loss<<<dim3(16, BB), 1024, 0, stream>>>(loc_preds, cls_preds, priorbox, targets,
                                              bto, bti, keys, h1, npos_r, pcr, locr);
    k_sel2<<<dim3(4, BB), 1024, 0, stream>>>(keys, h1, npos_r, h2, kimg);
    k_sel3<<<dim3(4, BB), 1024, 0, stream>>>(keys, h1, h2, npos_r, h3);
    k_neg<<<dim3(16, BB), 1024, 0, stream>>>(keys, h1, h2, h3, npos_r, negsum,
                                             Kstar, needeq);
    k_final<<<1, 64, 0, stream>>>(npos_r, kimg, pcr, negsum, locr, Kstar, needeq, out);
}

// Round 5
// 108.020 us; speedup vs baseline: 9.2870x; 1.0444x over previous
//
#include <hip/hip_runtime.h>

#define BB 16
#define PP 131072
#define GG 64
#define THRESH 0.35f
#define RMAX 0.086f          // max prior half-extent 0.085 + float-slop margin
#define NCELL 64             // 64x64 spatial grid, cell = 1/64

// ---------------- workspace layout (bytes) ----------------
#define OFF_BESTPK   0         // u64[BB*GG]     8192
#define OFF_H1       8192      // u32[BB*4096]   262144
#define OFF_H2       270336    // u32[BB*1024]   65536
#define OFF_H3       335872    // u32[BB*1024]   65536
#define OFF_NPOSR    401408    // i32[16][BB]    1024
#define OFF_PCR      402432    // f32[16][BB]    1024
#define OFF_LOCR     403456    // f32[16][BB]    1024
#define OFF_NEGS     404480    // f32[BB]        64
#define OFF_KIMG     404544    // i32[BB]        64
#define OFF_KSTAR    404608    // u32[BB]        64
#define OFF_NEEDEQ   404672    // i32[BB]        64
#define ZERO_BYTES   404736
#define ZERO_DWORDS  (ZERO_BYTES / 4)
#define OFF_KEYS     404736    // u32[BB*PP]     8388608
#define OFF_BTO      8793344   // f32[BB*PP]     8388608
#define OFF_BTI      17181952  // u8 [BB*PP]     2097152
#define OFF_MASK     19279104  // u64[BB*4096]   524288   (total ~19.8 MB)

// ---------------- gt-bitmask grid build + workspace zeroing ----------------
// grid (16, BB) x 256. Also zeros the accumulator region (replaces
// hipMemsetAsync: rocclr's fillBufferAligned ran at 10 GB/s -> 40 us for 405 KB).
__global__ __launch_bounds__(256) void k_build_mask(
    const float* __restrict__ targets, unsigned long long* __restrict__ gmask,
    unsigned* __restrict__ zbase)
{
    const int b = blockIdx.y;
    const int tid = threadIdx.x;
    // zero accumulators: 101184 dwords over 65536 threads (2 each max)
    const int gid = (b * 16 + blockIdx.x) * 256 + tid;
    for (int i = gid; i < ZERO_DWORDS; i += 16 * BB * 256) zbase[i] = 0u;

    __shared__ float sx1[GG], sy1[GG], sx2[GG], sy2[GG];
    if (tid < GG) {
        const float* t = targets + (size_t)(b * GG + tid) * 5;
        sx1[tid] = t[1] - RMAX; sy1[tid] = t[0] - RMAX;   // gts = t[[1,0,3,2]]
        sx2[tid] = t[3] + RMAX; sy2[tid] = t[2] + RMAX;
    }
    __syncthreads();
    const int cell = blockIdx.x * 256 + tid;
    const int cxi = cell & (NCELL - 1), cyi = cell >> 6;
    const float cx0 = cxi * (1.f / NCELL), cx1 = cx0 + (1.f / NCELL);
    const float cy0 = cyi * (1.f / NCELL), cy1 = cy0 + (1.f / NCELL);
    unsigned long long m = 0ull;
    for (int g = 0; g < GG; g++) {
        bool in = (sx1[g] < cx1) && (sx2[g] > cx0) && (sy1[g] < cy1) && (sy2[g] > cy0);
        m |= in ? (1ull << g) : 0ull;
    }
    gmask[(size_t)b * 4096 + cell] = m;
}

// ---------------- match kernel (mask-pruned) ----------------
// grid (PP/2048, BB), block 256; 8 priors/thread; per prior iterate only the
// ~4 gts whose expanded box covers the prior's cell. Zero-IoU pairs are
// irrelevant: bti matters only when bto>=THRESH, and each gt's best prior
// has IoU>0 with probability 1.
__global__ __launch_bounds__(256) void k_match(
    const float* __restrict__ priorbox, const float* __restrict__ targets,
    const unsigned long long* __restrict__ gmask,
    unsigned long long* __restrict__ bestpk, float* __restrict__ bto,
    unsigned char* __restrict__ bti)
{
    __shared__ float4 gxy[GG];
    __shared__ float gar[GG];
    __shared__ unsigned long long sbest[GG];
    const int b = blockIdx.y;
    const int tid = threadIdx.x;
    if (tid < GG) {
        const float* t = targets + (size_t)(b * GG + tid) * 5;
        float x1 = t[1], y1 = t[0], x2 = t[3], y2 = t[2];
        gxy[tid] = make_float4(x1, y1, x2, y2);
        gar[tid] = (x2 - x1) * (y2 - y1);
        sbest[tid] = 0ull;
    }
    __syncthreads();

    const int pbase = blockIdx.x * 2048 + tid;
    const unsigned long long* mrow = gmask + (size_t)b * 4096;

#pragma unroll
    for (int j = 0; j < 8; j++) {
        const int p = pbase + j * 256;
        float4 pr = *reinterpret_cast<const float4*>(priorbox + (size_t)p * 4);
        float hx = 0.5f * pr.z, hy = 0.5f * pr.w;
        float px1 = pr.x - hx, py1 = pr.y - hy;
        float px2 = pr.x + hx, py2 = pr.y + hy;
        float par = (px2 - px1) * (py2 - py1);          // matches reference rounding
        int cx = (int)(pr.x * (float)NCELL); cx = cx > 63 ? 63 : cx;
        int cy = (int)(pr.y * (float)NCELL); cy = cy > 63 ? 63 : cy;
        unsigned long long m = mrow[cy * NCELL + cx];
        const unsigned long long notp = (unsigned long long)(~(unsigned)p);
        float bv = -1.f; int bg = 0;
        while (m) {
            const int g = __ffsll((unsigned long long)m) - 1;   // ascending g => first-max tiebreak
            m &= m - 1;
            float4 a = gxy[g];
            float w = fminf(a.z, px2) - fmaxf(a.x, px1);
            float h = fminf(a.w, py2) - fmaxf(a.y, py1);
            w = fmaxf(w, 0.f); h = fmaxf(h, 0.f);
            float inter = w * h;
            float v = inter * __builtin_amdgcn_rcpf(gar[g] + par - inter);
            if (v > bv) { bv = v; bg = g; }
            if (v > 0.f) {
                unsigned long long pk =
                    (((unsigned long long)__float_as_uint(v)) << 32) | notp;
                atomicMax(&sbest[g], pk);
            }
        }
        bto[(size_t)b * PP + p] = bv;
        bti[(size_t)b * PP + p] = (unsigned char)bg;
    }

    __syncthreads();
    if (tid < GG) atomicMax(&bestpk[b * GG + tid], sbest[tid]);
}

// ---------------- decode best priors + override ----------------
__global__ void k_decode(const unsigned long long* __restrict__ bestpk,
                         float* __restrict__ bto, unsigned char* __restrict__ bti)
{
    __shared__ unsigned long long spk[GG];
    const int b = blockIdx.x;
    spk[threadIdx.x] = bestpk[b * GG + threadIdx.x];
    __syncthreads();
    if (threadIdx.x == 0) {
        for (int g = 0; g < GG; g++) {                    // serial: later g wins
            unsigned p = ~((unsigned)(spk[g] & 0xFFFFFFFFull));
            bto[(size_t)b * PP + p] = 2.0f;
            bti[(size_t)b * PP + p] = (unsigned char)g;
        }
    }
}

// ---------------- loss pass (keys + pos sums + h1 histogram) ----------------
// grid (16, BB), block 1024, 8 priors/thread strided by 1024
__global__ __launch_bounds__(1024) void k_loss(
    const float* __restrict__ loc_preds, const float* __restrict__ cls_preds,
    const float* __restrict__ priorbox, const float* __restrict__ targets,
    const float* __restrict__ bto, const unsigned char* __restrict__ bti,
    unsigned* __restrict__ keys, unsigned* __restrict__ h1,
    int* __restrict__ npos_r, float* __restrict__ poscls_r, float* __restrict__ locsum_r)
{
    __shared__ float gx1[GG], gy1[GG], gx2[GG], gy2[GG], glab[GG];
    __shared__ unsigned hist[4096];
    __shared__ float sred[32];
    __shared__ int sredi[16];
    const int b = blockIdx.y;
    const int tid = threadIdx.x;
    for (int i = tid; i < 4096; i += 1024) hist[i] = 0;
    if (tid < GG) {
        const float* t = targets + (size_t)(b * GG + tid) * 5;
        gx1[tid] = t[1]; gy1[tid] = t[0]; gx2[tid] = t[3]; gy2[tid] = t[2];
        glab[tid] = t[4];
    }
    __syncthreads();

    const int pbase = blockIdx.x * 8192 + tid;
    float locpart = 0.f, clspart = 0.f; int cnt = 0;

#pragma unroll
    for (int j = 0; j < 8; j++) {
        const int p = pbase + j * 1024;
        const size_t ip = (size_t)b * PP + p;
        const float bv = bto[ip];
        const int g = bti[ip];
        const float2 cl = *reinterpret_cast<const float2*>(cls_preds + ip * 2);
        const float mx = fmaxf(cl.x, cl.y);
        const float lse = mx + log1pf(expf(fminf(cl.x, cl.y) - mx));
        const float conf = (bv < THRESH) ? 0.f : glab[g];
        unsigned key = 0u;
        if (conf > 0.f) {
            float gathered = (((int)conf) == 0) ? cl.x : cl.y;
            clspart += lse - gathered;
            cnt++;
            float4 pr = *reinterpret_cast<const float4*>(priorbox + (size_t)p * 4);
            float mx1 = gx1[g], my1 = gy1[g], mx2 = gx2[g], my2 = gy2[g];
            float gcx = ((mx1 + mx2) * 0.5f - pr.x) / (0.1f * pr.z);
            float gcy = ((my1 + my2) * 0.5f - pr.y) / (0.1f * pr.w);
            float gw = logf((mx2 - mx1) / pr.z) / 0.2f;
            float gh = logf((my2 - my1) / pr.w) / 0.2f;
            float4 lp = *reinterpret_cast<const float4*>(loc_preds + ip * 4);
            float d0 = lp.x - gcx, d1 = lp.y - gcy, d2 = lp.z - gw, d3 = lp.w - gh;
            float a0 = fabsf(d0), a1 = fabsf(d1), a2 = fabsf(d2), a3 = fabsf(d3);
            locpart += ((a0 < 1.f) ? 0.5f * d0 * d0 : a0 - 0.5f)
                     + ((a1 < 1.f) ? 0.5f * d1 * d1 : a1 - 0.5f)
                     + ((a2 < 1.f) ? 0.5f * d2 * d2 : a2 - 0.5f)
                     + ((a3 < 1.f) ? 0.5f * d3 * d3 : a3 - 0.5f);
        } else {
            key = __float_as_uint(lse - cl.x);            // loss_c > 0 strictly for negs
        }
        keys[ip] = key;
        atomicAdd(&hist[key >> 20], 1u);
    }

    for (int o = 32; o; o >>= 1) {
        locpart += __shfl_xor(locpart, o);
        clspart += __shfl_xor(clspart, o);
        cnt     += __shfl_xor(cnt, o);
    }
    const int w = tid >> 6;
    if ((tid & 63) == 0) { sred[w] = locpart; sred[16 + w] = clspart; sredi[w] = cnt; }
    __syncthreads();
    if (tid == 0) {
        float l = 0.f, c = 0.f; int n = 0;
        for (int i = 0; i < 16; i++) { l += sred[i]; c += sred[16 + i]; n += sredi[i]; }
        const int rep = blockIdx.x * BB + b;
        if (n)        atomicAdd(&npos_r[rep], n);
        if (c != 0.f) atomicAdd(&poscls_r[rep], c);
        if (l != 0.f) atomicAdd(&locsum_r[rep], l);
    }
    __syncthreads();
    for (int i = tid; i < 4096; i += 1024) {
        unsigned cc = hist[i];
        if (cc) atomicAdd(&h1[b * 4096 + i], cc);
    }
}

// ---------------- parallel descending k-th finder (block of 1024) ----------------
template <int NBINS>
__device__ void find_kth_par(const unsigned* __restrict__ h, int k, int* sel, int* krem)
{
    constexpr int PER = NBINS / 1024;
    __shared__ unsigned wsum_[16];
    __shared__ int res_[2];
    const int tid = threadIdx.x, lane = tid & 63, wid = tid >> 6;
    __syncthreads();                         // protect LDS reuse across calls
    unsigned own[PER];
    unsigned s = 0;
#pragma unroll
    for (int i = 0; i < PER; i++) { own[i] = h[NBINS - 1 - (tid * PER + i)]; s += own[i]; }
    unsigned incl = s;
    for (int d = 1; d < 64; d <<= 1) {
        unsigned t = __shfl_up(incl, d);
        if (lane >= d) incl += t;
    }
    if (lane == 63) wsum_[wid] = incl;
    if (tid == 0) { res_[0] = -1; res_[1] = 0; }
    __syncthreads();
    unsigned woff = 0;
    for (int w = 0; w < 16; w++) woff += (w < wid) ? wsum_[w] : 0u;
    const unsigned texcl = woff + incl - s;
    if (k > 0 && texcl < (unsigned)k && texcl + s >= (unsigned)k) {
        unsigned run = texcl;
#pragma unroll
        for (int i = 0; i < PER; i++) {
            run += own[i];
            if (run >= (unsigned)k) {
                res_[0] = NBINS - 1 - (tid * PER + i);
                res_[1] = k - (int)(run - own[i]);
                break;
            }
        }
    }
    __syncthreads();
    *sel = res_[0]; *krem = res_[1];
}

// ---------------- pass 2: scan1 (redundant per block) + h2 build ----------------
// grid (4, BB) x 1024, 32 keys/thread
__global__ __launch_bounds__(1024) void k_sel2(
    const unsigned* __restrict__ keys, const unsigned* __restrict__ h1,
    const int* __restrict__ npos_r, unsigned* __restrict__ h2,
    int* __restrict__ kimg)
{
    __shared__ unsigned hist[1024];
    const int b = blockIdx.y, tid = threadIdx.x;
    hist[tid] = 0;
    int np = 0;
    for (int r = 0; r < 16; r++) np += npos_r[r * BB + b];
    const int k = min(3 * np, PP - 1);
    int sel, krem;
    find_kth_par<4096>(h1 + b * 4096, k, &sel, &krem);
    if (blockIdx.x == 0 && tid == 0) kimg[b] = k;
    const unsigned s = (unsigned)sel;                    // -1 -> matches nothing
    const size_t base = (size_t)b * PP + (size_t)blockIdx.x * 32768;
    for (int j = 0; j < 32; j++) {
        unsigned key = keys[base + j * 1024 + tid];
        if ((key >> 20) == s) atomicAdd(&hist[(key >> 10) & 1023u], 1u);
    }
    __syncthreads();
    unsigned c = hist[tid];
    if (c) atomicAdd(&h2[b * 1024 + tid], c);
}

// ---------------- pass 3: scan1+scan2 (redundant) + h3 build ----------------
__global__ __launch_bounds__(1024) void k_sel3(
    const unsigned* __restrict__ keys, const unsigned* __restrict__ h1,
    const unsigned* __restrict__ h2, const int* __restrict__ npos_r,
    unsigned* __restrict__ h3)
{
    __shared__ unsigned hist[1024];
    const int b = blockIdx.y, tid = threadIdx.x;
    hist[tid] = 0;
    int np = 0;
    for (int r = 0; r < 16; r++) np += npos_r[r * BB + b];
    const int k = min(3 * np, PP - 1);
    int sel1, kk1, sel2, kk2;
    find_kth_par<4096>(h1 + b * 4096, k, &sel1, &kk1);
    find_kth_par<1024>(h2 + b * 1024, kk1, &sel2, &kk2);
    const unsigned top = ((unsigned)sel1 << 10) | ((unsigned)sel2 & 1023u);
    const size_t base = (size_t)b * PP + (size_t)blockIdx.x * 32768;
    for (int j = 0; j < 32; j++) {
        unsigned key = keys[base + j * 1024 + tid];
        if ((key >> 10) == top) atomicAdd(&hist[key & 1023u], 1u);
    }
    __syncthreads();
    unsigned c = hist[tid];
    if (c) atomicAdd(&h3[b * 1024 + tid], c);
}

// ---------------- neg-sum: full scan chain (redundant) + selected-key sum ----------------
// grid (16, BB) x 1024, 8 keys/thread
__global__ __launch_bounds__(1024) void k_neg(
    const unsigned* __restrict__ keys, const unsigned* __restrict__ h1,
    const unsigned* __restrict__ h2, const unsigned* __restrict__ h3,
    const int* __restrict__ npos_r, float* __restrict__ negsum,
    unsigned* __restrict__ KstarA, int* __restrict__ needeqA)
{
    __shared__ float sred[16];
    const int b = blockIdx.y, tid = threadIdx.x;
    int np = 0;
    for (int r = 0; r < 16; r++) np += npos_r[r * BB + b];
    const int k = min(3 * np, PP - 1);
    int sel1, kk1, sel2, kk2, sel3, krem3;
    find_kth_par<4096>(h1 + b * 4096, k, &sel1, &kk1);
    find_kth_par<1024>(h2 + b * 1024, kk1, &sel2, &kk2);
    find_kth_par<1024>(h3 + b * 1024, kk2, &sel3, &krem3);
    unsigned Kstar; int needeq;
    if (sel3 < 0) { Kstar = 0xFFFFFFFFu; needeq = 0; }
    else {
        Kstar = ((unsigned)sel1 << 20) | ((unsigned)sel2 << 10) | (unsigned)sel3;
        needeq = krem3;
    }
    if (blockIdx.x == 0 && tid == 0) { KstarA[b] = Kstar; needeqA[b] = needeq; }
    const size_t base = (size_t)b * PP + (size_t)blockIdx.x * 8192;
    float v = 0.f;
#pragma unroll
    for (int j = 0; j < 8; j++) {
        unsigned key = keys[base + j * 1024 + tid];
        if (key > Kstar) v += __uint_as_float(key);
    }
    for (int o = 32; o; o >>= 1) v += __shfl_xor(v, o);
    if ((tid & 63) == 0) sred[tid >> 6] = v;
    __syncthreads();
    if (tid == 0) {
        float s2 = 0.f;
        for (int w2 = 0; w2 < 16; w2++) s2 += sred[w2];
        if (s2 != 0.f) atomicAdd(&negsum[b], s2);
    }
}

__global__ void k_final(const int* __restrict__ npos_r, const int* __restrict__ kimg,
                        const float* __restrict__ poscls_r, const float* __restrict__ negsum,
                        const float* __restrict__ locsum_r, const unsigned* __restrict__ Kstar,
                        const int* __restrict__ needeq, float* __restrict__ out)
{
    if (threadIdx.x == 0 && blockIdx.x == 0) {
        int npt = 0; long long maskc = 0; float clsnum = 0.f, locnum = 0.f;
        for (int b = 0; b < BB; b++) {
            int nb = 0; float pc = 0.f, lc = 0.f;
            for (int r = 0; r < 16; r++) {
                nb += npos_r[r * BB + b];
                pc += poscls_r[r * BB + b];
                lc += locsum_r[r * BB + b];
            }
            npt += nb;
            maskc += (long long)nb + kimg[b];
            float add = (needeq[b] > 0) ? needeq[b] * __uint_as_float(Kstar[b]) : 0.f;
            clsnum += pc + negsum[b] + add;
            locnum += lc;
        }
        float denom_loc = (float)((4 * npt > 1) ? 4 * npt : 1);
        float denom_cls = (float)((maskc > 1) ? maskc : 1);
        float loss_loc = locnum / denom_loc;
        float loss_cls = clsnum / denom_cls;
        float loss = (loss_cls + loss_loc) / (float)npt;
        out[0] = loss; out[1] = loss_loc; out[2] = loss_cls;
    }
}

extern "C" void kernel_launch(void* const* d_in, const int* in_sizes, int n_in,
                              void* d_out, int out_size, void* d_ws, size_t ws_size,
                              hipStream_t stream)
{
    const float* loc_preds = (const float*)d_in[0];
    const float* cls_preds = (const float*)d_in[1];
    const float* priorbox  = (const float*)d_in[2];
    const float* targets   = (const float*)d_in[3];
    float* out = (float*)d_out;

    char* ws = (char*)d_ws;
    unsigned long long* bestpk = (unsigned long long*)(ws + OFF_BESTPK);
    unsigned* h1     = (unsigned*)(ws + OFF_H1);
    unsigned* h2     = (unsigned*)(ws + OFF_H2);
    unsigned* h3     = (unsigned*)(ws + OFF_H3);
    int*      npos_r = (int*)(ws + OFF_NPOSR);
    float*    pcr    = (float*)(ws + OFF_PCR);
    float*    locr   = (float*)(ws + OFF_LOCR);
    float*    negsum = (float*)(ws + OFF_NEGS);
    int*      kimg   = (int*)(ws + OFF_KIMG);
    unsigned* Kstar  = (unsigned*)(ws + OFF_KSTAR);
    int*      needeq = (int*)(ws + OFF_NEEDEQ);
    unsigned* keys   = (unsigned*)(ws + OFF_KEYS);
    float*    bto    = (float*)(ws + OFF_BTO);
    unsigned char* bti = (unsigned char*)(ws + OFF_BTI);
    unsigned long long* gmask = (unsigned long long*)(ws + OFF_MASK);

    k_build_mask<<<dim3(16, BB), 256, 0, stream>>>(targets, gmask, (unsigned*)ws);
    k_match<<<dim3(PP / 2048, BB), 256, 0, stream>>>(priorbox, targets, gmask,
                                                     bestpk, bto, bti);
    k_decode<<<BB, 64, 0, stream>>>(bestpk, bto, bti);
    k_loss<<<dim3(16, BB), 1024, 0, stream>>>(loc_preds, cls_preds, priorbox, targets,
                                              bto, bti, keys, h1, npos_r, pcr, locr);
    k_sel2<<<dim3(4, BB), 1024, 0, stream>>>(keys, h1, npos_r, h2, kimg);
    k_sel3<<<dim3(4, BB), 1024, 0, stream>>>(keys, h1, h2, npos_r, h3);
    k_neg<<<dim3(16, BB), 1024, 0, stream>>>(keys, h1, h2, h3, npos_r, negsum,
                                             Kstar, needeq);
    k_final<<<1, 64, 0, stream>>>(npos_r, kimg, pcr, negsum, locr, Kstar, needeq, out);
}